// Round 1
// 1601.397 us; speedup vs baseline: 1.2310x; 1.2310x over previous
//
#include <hip/hip_runtime.h>

// Problem constants
#define LL   8
#define HH   4
#define QQ   64
#define DD   512
#define NN   2048
#define DFFC 2048
#define ENTRY_CAP (1 << 17)
#define CHUNK 8
#define APPLY_BLOCKS 2048
#define LCAP 2048   // per-block LDS entry staging capacity

typedef short     bf16x8 __attribute__((ext_vector_type(8)));  // 8 bf16 = 4 VGPR
typedef float     f32x4  __attribute__((ext_vector_type(4)));  // MFMA C/D frag
typedef unsigned short u16;

// fp32 -> (hi, lo) bf16 split, RNE. x ~= hi + lo with ~16-bit mantissa coverage.
__device__ inline void splitf(float v, u16& h, u16& l)
{
    unsigned u  = __float_as_uint(v);
    unsigned uh = u + (0x7FFFu + ((u >> 16) & 1u));
    h = (u16)(uh >> 16);
    float fh = __uint_as_float(((unsigned)h) << 16);
    float r  = v - fh;
    unsigned ur = __float_as_uint(r);
    unsigned ul = ur + (0x7FFFu + ((ur >> 16) & 1u));
    l = (u16)(ul >> 16);
}

// Monotone fp32 <-> uint mapping for atomicMax on floats (no NaNs in data).
__device__ inline unsigned mapf(float f)
{
    unsigned u = __float_as_uint(f);
    return (u >> 31) ? ~u : (u | 0x80000000u);
}
__device__ inline float unmapf(unsigned u)
{
    return (u >> 31) ? __uint_as_float(u ^ 0x80000000u) : __uint_as_float(~u);
}

// ---------------------------------------------------------------------------
// Split-bf16 MFMA GEMM (NT): C[M,N] = A[M,K] @ B[N,K]^T as hi*hi+hi*lo+lo*hi
// (fp32 accumulate).
//
// NEW (this round): LDS-staged m97 structure. Block = 256 thr = 4 waves
// (2x2), block tile (MI*32) x 128, BK=32, double-buffered LDS filled with
// __builtin_amdgcn_global_load_lds width=16 (direct HBM/L2 -> LDS, no VGPR
// round-trip). One __syncthreads per K-step (T3 minimum 2-phase: issue
// next-tile staging BEFORE ds_read+MFMA of current tile).
//
// Rationale: the old direct-global fragment loads needed ~280 B/cy/CU from
// L2 vs the ~56 B/cy/CU ceiling -> structurally capped at ~20% MfmaUtil
// (measured 10.7%). LDS staging cuts traffic to 32 KB per iter vs 931
// MFMA-cycles -> 35 B/cy/CU, under the ceiling.
//
// LDS bank swizzle (rule 21: both-sides-or-neither with global_load_lds):
// within each 64B row (4 chunks of 16B), chunk c is stored at linear c but
// holds global chunk c ^ f(r), f(r) = (r&3)^((r>>2)&3). The ds_read side
// reads chunk quad ^ f(r). f depends only on row bits 0..3 (= l15 on the
// read side), which spreads the 16 lanes of each quad-group 2-per-bank-start
// -> balanced 8-dwords-per-bank (conflict-free for b128).
// K must be a multiple of 32. M multiple of MI*32, N multiple of 128.
// ---------------------------------------------------------------------------
template <int MI, int BIAS, int RELU, int WF32, int WSPLIT>
__global__ __launch_bounds__(256, 2) void mgemm_k(
    const u16* __restrict__ Ahi, const u16* __restrict__ Alo,
    const u16* __restrict__ Bhi, const u16* __restrict__ Blo,
    float* __restrict__ C, u16* __restrict__ Chi, u16* __restrict__ Clo,
    const float* __restrict__ bias,
    int M, int N, int K, int lda, int ldb, int ldc,
    long sAoff, long sBoff, long sCoff)
{
    constexpr int ACH = MI * 128;        // 16B chunks per A stream per BK-tile
    constexpr int TOT = 2 * ACH + 1024;  // chunks per buffer (Ahi|Alo|Bhi|Blo)
    // MI=4: 2*2048*16B = 64 KB (exactly the static-shared limit); MI=1: 40 KB
    __shared__ __align__(16) u16 smem[2 * TOT * 8];

    const int bz = blockIdx.z;
    Ahi += bz * sAoff;  Alo += bz * sAoff;
    Bhi += bz * sBoff;  Blo += bz * sBoff;
    const long cOff = (long)bz * sCoff;

    const int tid  = threadIdx.x;
    const int wave = tid >> 6, lane = tid & 63;
    const int quad = lane >> 4, l15 = lane & 15;
    const int wy = wave >> 1, wx = wave & 1;
    const long mTile = (long)blockIdx.y * (MI * 32);
    const long nTile = (long)blockIdx.x * 128;
    const int mBase = (int)mTile + wy * (MI * 16);
    const int nBase = (int)nTile + wx * 64;

    // fragment-read chunk swizzle: row bits 0..3 == l15 for all frag rows
    const int fsw = (l15 & 3) ^ ((l15 >> 2) & 3);
    const int cA  = (quad ^ fsw) * 8;    // u16 offset of this lane's 16B chunk

// Stage one BK=32 tile (all 4 streams) into LDS buffer `bufi`.
// idx = s*256+tid: within a wave-issue all 64 lanes share one stream
// (stream boundaries are multiples of 64 chunks) -> wave-uniform LDS base.
// Global source address carries the inverse swizzle (c ^ f(r)).
#define STAGE(bufi, koff)                                                     \
    {                                                                         \
        _Pragma("unroll")                                                     \
        for (int s = 0; s < TOT / 256; s++) {                                 \
            const int idx = s * 256 + tid;                                    \
            const u16* sp;  long rowb;  int ldx;  int rel;                    \
            if (idx < ACH)                { sp = Ahi; rel = idx;               rowb = mTile; ldx = lda; } \
            else if (idx < 2 * ACH)       { sp = Alo; rel = idx - ACH;         rowb = mTile; ldx = lda; } \
            else if (idx < 2 * ACH + 512) { sp = Bhi; rel = idx - 2 * ACH;     rowb = nTile; ldx = ldb; } \
            else                          { sp = Blo; rel = idx - 2*ACH - 512; rowb = nTile; ldx = ldb; } \
            const int r = rel >> 2;                                           \
            const int c = (rel & 3) ^ ((r & 3) ^ ((r >> 2) & 3));             \
            const u16* g = sp + (rowb + r) * (long)ldx + (koff) + c * 8;      \
            u16* lp = (u16*)smem + (bufi) * (TOT * 8) + idx * 8;              \
            __builtin_amdgcn_global_load_lds(                                 \
                (const __attribute__((address_space(1))) void*)g,             \
                (__attribute__((address_space(3))) void*)lp, 16, 0, 0);       \
        }                                                                     \
    }

    f32x4 acc[MI][4];
#pragma unroll
    for (int i = 0; i < MI; i++)
#pragma unroll
        for (int j = 0; j < 4; j++)
            acc[i][j] = (f32x4){0.f, 0.f, 0.f, 0.f};

    STAGE(0, 0)
    int buf = 0;
    const int NT = K >> 5;
    for (int t = 0; t < NT; t++) {
        __syncthreads();                 // buf staged (vmcnt drain) + prev reads done
        if (t + 1 < NT) STAGE(buf ^ 1, (t + 1) << 5)

        const u16* Lb = (const u16*)smem + buf * (TOT * 8);
        bf16x8 ah[MI], al[MI], bh[4], bl[4];
#pragma unroll
        for (int i = 0; i < MI; i++) {
            const int off = (wy * (MI * 16) + i * 16 + l15) * 32 + cA;
            ah[i] = *(const bf16x8*)(Lb + off);
            al[i] = *(const bf16x8*)(Lb + ACH * 8 + off);
        }
#pragma unroll
        for (int j = 0; j < 4; j++) {
            const int off = (wx * 64 + j * 16 + l15) * 32 + cA;
            bh[j] = *(const bf16x8*)(Lb + 2 * ACH * 8 + off);
            bl[j] = *(const bf16x8*)(Lb + 2 * ACH * 8 + 512 * 8 + off);
        }

#pragma unroll
        for (int i = 0; i < MI; i++)
#pragma unroll
            for (int j = 0; j < 4; j++) {
                acc[i][j] = __builtin_amdgcn_mfma_f32_16x16x32_bf16(
                    ah[i], bh[j], acc[i][j], 0, 0, 0);
                acc[i][j] = __builtin_amdgcn_mfma_f32_16x16x32_bf16(
                    ah[i], bl[j], acc[i][j], 0, 0, 0);
                acc[i][j] = __builtin_amdgcn_mfma_f32_16x16x32_bf16(
                    al[i], bh[j], acc[i][j], 0, 0, 0);
            }
        buf ^= 1;
    }
#undef STAGE

#pragma unroll
    for (int i = 0; i < MI; i++) {
#pragma unroll
        for (int j = 0; j < 4; j++) {
            const int n = nBase + j * 16 + l15;
            const float bv = BIAS ? bias[n] : 0.0f;
#pragma unroll
            for (int r = 0; r < 4; r++) {
                const int m = mBase + i * 16 + quad * 4 + r;
                float v = acc[i][j][r] + bv;
                if (RELU) v = fmaxf(v, 0.0f);
                const long o = cOff + (long)m * ldc + n;
                if (WF32) C[o] = v;
                if (WSPLIT) {
                    u16 h, l;
                    splitf(v, h, l);
                    Chi[o] = h;
                    Clo[o] = l;
                }
            }
        }
    }
}

// ---------------------------------------------------------------------------
// Fused mask path, pass A: per-head Gram tile S = G G^T in regs; row-max
// reduce -> global atomicMax. K=64: ALL fragments (both k-steps) preloaded
// before any MFMA (full ILP). UNCHANGED this round (must stay bit-identical
// to sextract_k's recompute).
// ---------------------------------------------------------------------------
__global__ __launch_bounds__(256) void smax_k(
    const u16* __restrict__ Ghi, const u16* __restrict__ Glo,
    unsigned* __restrict__ rowmaxU)
{
    const int h = blockIdx.z;
    const u16* Ah = Ghi + h * QQ;
    const u16* Al = Glo + h * QQ;
    const int lda = HH * QQ;

    const int tid  = threadIdx.x;
    const int wave = tid >> 6, lane = tid & 63;
    const int quad = lane >> 4, l15 = lane & 15;
    const int wy = wave >> 1, wx = wave & 1;
    const int rB = blockIdx.y * 128 + wy * 64;
    const int cB = blockIdx.x * 128 + wx * 64;

    bf16x8 ah[2][4], al[2][4], bh[2][4], bl[2][4];
#pragma unroll
    for (int s = 0; s < 2; s++) {
        const int kk = s * 32 + quad * 8;
#pragma unroll
        for (int i = 0; i < 4; i++) {
            long ar = (long)(rB + i * 16 + l15) * lda + kk;
            ah[s][i] = *(const bf16x8*)(Ah + ar);
            al[s][i] = *(const bf16x8*)(Al + ar);
            long br = (long)(cB + i * 16 + l15) * lda + kk;
            bh[s][i] = *(const bf16x8*)(Ah + br);
            bl[s][i] = *(const bf16x8*)(Al + br);
        }
    }

    f32x4 acc[4][4];
#pragma unroll
    for (int i = 0; i < 4; i++)
#pragma unroll
        for (int j = 0; j < 4; j++)
            acc[i][j] = (f32x4){0.f, 0.f, 0.f, 0.f};

#pragma unroll
    for (int s = 0; s < 2; s++)
#pragma unroll
        for (int i = 0; i < 4; i++)
#pragma unroll
            for (int j = 0; j < 4; j++) {
                acc[i][j] = __builtin_amdgcn_mfma_f32_16x16x32_bf16(ah[s][i], bh[s][j], acc[i][j], 0, 0, 0);
                acc[i][j] = __builtin_amdgcn_mfma_f32_16x16x32_bf16(ah[s][i], bl[s][j], acc[i][j], 0, 0, 0);
                acc[i][j] = __builtin_amdgcn_mfma_f32_16x16x32_bf16(al[s][i], bh[s][j], acc[i][j], 0, 0, 0);
            }

#pragma unroll
    for (int i = 0; i < 4; i++)
#pragma unroll
        for (int r = 0; r < 4; r++) {
            float mx = acc[i][0][r];
#pragma unroll
            for (int j = 1; j < 4; j++) mx = fmaxf(mx, acc[i][j][r]);
#pragma unroll
            for (int off = 1; off < 16; off <<= 1)
                mx = fmaxf(mx, __shfl_xor(mx, off, 64));
            if (l15 == 0)
                atomicMax(&rowmaxU[h * NN + rB + i * 16 + quad * 4 + r], mapf(mx));
        }
}

// ---------------------------------------------------------------------------
// Fused mask path, pass B: recompute IDENTICAL S tile (same per-(i,j) MFMA
// order as smax -> same bits), threshold, count, emit entries via LDS
// staging + one global atomicAdd per block. Full fragment preload (K=64).
// ---------------------------------------------------------------------------
__global__ __launch_bounds__(256) void sextract_k(
    const u16* __restrict__ Ghi, const u16* __restrict__ Glo,
    const unsigned* __restrict__ rowmaxU, int* __restrict__ rowcnt,
    unsigned int* __restrict__ entries, int* __restrict__ counter)
{
    const int h = blockIdx.z;
    const u16* Ah = Ghi + h * QQ;
    const u16* Al = Glo + h * QQ;
    const int lda = HH * QQ;

    const int tid  = threadIdx.x;
    const int wave = tid >> 6, lane = tid & 63;
    const int quad = lane >> 4, l15 = lane & 15;
    const int wy = wave >> 1, wx = wave & 1;
    const int rB = blockIdx.y * 128 + wy * 64;
    const int cB = blockIdx.x * 128 + wx * 64;

    __shared__ float thrS[128];
    __shared__ unsigned lbuf[LCAP];
    __shared__ int lcnt, gbase;
    if (tid == 0) lcnt = 0;
    if (tid < 128) {
        float mx = unmapf(rowmaxU[h * NN + blockIdx.y * 128 + tid]);
        thrS[tid] = (fabsf(mx) > 0.5f) ? mx - 0.5f : 3.402823466e38f;
    }
    __syncthreads();

    bf16x8 ah[2][4], al[2][4], bh[2][4], bl[2][4];
#pragma unroll
    for (int s = 0; s < 2; s++) {
        const int kk = s * 32 + quad * 8;
#pragma unroll
        for (int i = 0; i < 4; i++) {
            long ar = (long)(rB + i * 16 + l15) * lda + kk;
            ah[s][i] = *(const bf16x8*)(Ah + ar);
            al[s][i] = *(const bf16x8*)(Al + ar);
            long br = (long)(cB + i * 16 + l15) * lda + kk;
            bh[s][i] = *(const bf16x8*)(Ah + br);
            bl[s][i] = *(const bf16x8*)(Al + br);
        }
    }

    f32x4 acc[4][4];
#pragma unroll
    for (int i = 0; i < 4; i++)
#pragma unroll
        for (int j = 0; j < 4; j++)
            acc[i][j] = (f32x4){0.f, 0.f, 0.f, 0.f};

#pragma unroll
    for (int s = 0; s < 2; s++)
#pragma unroll
        for (int i = 0; i < 4; i++)
#pragma unroll
            for (int j = 0; j < 4; j++) {
                acc[i][j] = __builtin_amdgcn_mfma_f32_16x16x32_bf16(ah[s][i], bh[s][j], acc[i][j], 0, 0, 0);
                acc[i][j] = __builtin_amdgcn_mfma_f32_16x16x32_bf16(ah[s][i], bl[s][j], acc[i][j], 0, 0, 0);
                acc[i][j] = __builtin_amdgcn_mfma_f32_16x16x32_bf16(al[s][i], bh[s][j], acc[i][j], 0, 0, 0);
            }

#pragma unroll
    for (int i = 0; i < 4; i++) {
#pragma unroll
        for (int r = 0; r < 4; r++) {
            const int lr  = wy * 64 + i * 16 + quad * 4 + r;
            const int row = h * NN + rB + i * 16 + quad * 4 + r;
            const float thr = thrS[lr];

            int c = 0;
#pragma unroll
            for (int j = 0; j < 4; j++) c += (acc[i][j][r] >= thr) ? 1 : 0;
            int cs = c;
#pragma unroll
            for (int off = 1; off < 16; off <<= 1) cs += __shfl_xor(cs, off, 64);
            if (l15 == 0 && cs > 0) atomicAdd(&rowcnt[row], cs);

#pragma unroll
            for (int j = 0; j < 4; j++) {
                if (acc[i][j][r] >= thr) {
                    unsigned ent = ((unsigned)row << 11) |
                                   (unsigned)(cB + j * 16 + l15);
                    int s2 = atomicAdd(&lcnt, 1);
                    if (s2 < LCAP) {
                        lbuf[s2] = ent;
                    } else {
                        unsigned p = (unsigned)atomicAdd(counter, 1);
                        if (p < ENTRY_CAP) entries[p] = ent;
                    }
                }
            }
        }
    }

    __syncthreads();
    int n = lcnt;
    if (n > LCAP) n = LCAP;
    if (n > 0) {
        if (tid == 0) gbase = atomicAdd(counter, n);
        __syncthreads();
        for (int i2 = tid; i2 < n; i2 += 256) {
            unsigned p = (unsigned)(gbase + i2);
            if (p < ENTRY_CAP) entries[p] = lbuf[i2];
        }
    }
}

// ---------------------------------------------------------------------------
// initrow / wrecip / split / splitw / zero / buildcsr / initattn / apply /
// ff2red / transpose  (unchanged)
// ---------------------------------------------------------------------------
__global__ __launch_bounds__(256) void initrow_k(unsigned* __restrict__ p)
{
    p[blockIdx.x * 256 + threadIdx.x] = 0u;
}

__global__ __launch_bounds__(256) void wrecip_k(
    const unsigned* __restrict__ rowmaxU, const int* __restrict__ rowcnt,
    float* __restrict__ wrecip)
{
    int i = blockIdx.x * 256 + threadIdx.x;
    float mx = unmapf(rowmaxU[i]);
    wrecip[i] = (fabsf(mx) > 0.5f) ? 1.0f / fmaxf((float)rowcnt[i], 1.0f) : 0.0f;
}

__global__ __launch_bounds__(256) void split_k(
    const float* __restrict__ src, u16* __restrict__ hi, u16* __restrict__ lo)
{
    int i = blockIdx.x * 256 + threadIdx.x;
    float4 v = ((const float4*)src)[i];
    ushort4 hv, lv;
    splitf(v.x, hv.x, lv.x);
    splitf(v.y, hv.y, lv.y);
    splitf(v.z, hv.z, lv.z);
    splitf(v.w, hv.w, lv.w);
    ((ushort4*)hi)[i] = hv;
    ((ushort4*)lo)[i] = lv;
}

__global__ __launch_bounds__(256) void splitw_k(
    const float* __restrict__ K_, const float* __restrict__ V_,
    const float* __restrict__ W1_, const float* __restrict__ W2_,
    u16* __restrict__ Khi, u16* __restrict__ Klo,
    u16* __restrict__ Vhi, u16* __restrict__ Vlo,
    u16* __restrict__ W1hi, u16* __restrict__ W1lo,
    u16* __restrict__ W2hi, u16* __restrict__ W2lo)
{
    int i = blockIdx.x * 256 + threadIdx.x;
    const float* s;
    u16 *h, *l;
    int off;
    if (i < 32768)       { s = K_;  h = Khi;  l = Klo;  off = i; }
    else if (i < 294912) { s = V_;  h = Vhi;  l = Vlo;  off = i - 32768; }
    else if (i < 557056) { s = W1_; h = W1hi; l = W1lo; off = i - 294912; }
    else                 { s = W2_; h = W2hi; l = W2lo; off = i - 557056; }
    float4 v = ((const float4*)s)[off];
    ushort4 hv, lv;
    splitf(v.x, hv.x, lv.x);
    splitf(v.y, hv.y, lv.y);
    splitf(v.z, hv.z, lv.z);
    splitf(v.w, hv.w, lv.w);
    ((ushort4*)h)[off] = hv;
    ((ushort4*)l)[off] = lv;
}

__global__ void zero_k(int* __restrict__ counters)
{
    if (threadIdx.x < LL) counters[threadIdx.x] = 0;
}

__global__ __launch_bounds__(256) void buildcsr_k(
    const unsigned int* __restrict__ entries, const int* __restrict__ counter,
    unsigned int* __restrict__ csr, int* __restrict__ colOff)
{
    __shared__ int hist[NN];
    __shared__ int part[256];
    const int t = threadIdx.x;
    int cnt = *counter;
    if (cnt > ENTRY_CAP) cnt = ENTRY_CAP;

    for (int i = t; i < NN; i += 256) hist[i] = 0;
    __syncthreads();
    for (int i = t; i < cnt; i += 256)
        atomicAdd(&hist[entries[i] & 2047], 1);
    __syncthreads();

    int e[8];
    int s = 0;
#pragma unroll
    for (int i = 0; i < 8; i++) { e[i] = s; s += hist[t * 8 + i]; }
    part[t] = s;
    __syncthreads();
    for (int off = 1; off < 256; off <<= 1) {
        int x = (t >= off) ? part[t - off] : 0;
        __syncthreads();
        part[t] += x;
        __syncthreads();
    }
    int base = (t > 0) ? part[t - 1] : 0;
    int my[8];
#pragma unroll
    for (int i = 0; i < 8; i++) my[i] = base + e[i];
#pragma unroll
    for (int i = 0; i < 8; i++) colOff[t * 8 + i] = my[i];
    if (t == 255) colOff[NN] = part[255];
    __syncthreads();
#pragma unroll
    for (int i = 0; i < 8; i++) hist[t * 8 + i] = my[i];
    __syncthreads();

    for (int i = t; i < cnt; i += 256) {
        unsigned v = entries[i];
        int slot = atomicAdd(&hist[v & 2047], 1);
        csr[slot] = v;
    }
}

__global__ __launch_bounds__(256) void initattn_k(
    const float* __restrict__ X, float* __restrict__ attnT)
{
    long i = (long)blockIdx.x * 256 + threadIdx.x;
    ((float4*)attnT)[i] = ((const float4*)X)[i];
}

__global__ __launch_bounds__(256) void apply_k(
    const unsigned int* __restrict__ csr, const int* __restrict__ colOff,
    const float* __restrict__ wrecip, const float* __restrict__ Yt,
    float* __restrict__ attnT)
{
    const int total = colOff[NN];
    const int tid = threadIdx.x;

    for (int base = blockIdx.x * CHUNK; base < total;
         base += gridDim.x * CHUNK) {
        int end = base + CHUNK;
        if (end > total) end = total;

        float a0 = 0.0f, a1 = 0.0f;
        int curM = -1;
        for (int e = base; e < end; e++) {
            unsigned v = csr[e];
            int m = v & 2047;
            int row = (int)(v >> 11);
            if (m != curM) {
                if (curM >= 0) {
                    atomicAdd(&attnT[(long)curM * DD + tid], a0);
                    atomicAdd(&attnT[(long)curM * DD + tid + 256], a1);
                }
                curM = m;
                a0 = a1 = 0.0f;
            }
            float w = wrecip[row];
            const float* y = Yt + (long)row * DD;
            a0 += w * y[tid];
            a1 += w * y[tid + 256];
        }
        if (curM >= 0) {
            atomicAdd(&attnT[(long)curM * DD + tid], a0);
            atomicAdd(&attnT[(long)curM * DD + tid + 256], a1);
        }
    }
}

__global__ __launch_bounds__(256) void ff2red_k(
    const float* __restrict__ Cpart, const float* __restrict__ b2,
    const float* __restrict__ attnT, float* __restrict__ Xn,
    u16* __restrict__ Xhi, u16* __restrict__ Xlo)
{
    int i = blockIdx.x * 256 + threadIdx.x;
    float4 v0 = ((const float4*)(Cpart))[i];
    float4 v1 = ((const float4*)(Cpart + 1048576))[i];
    float4 v2 = ((const float4*)(Cpart + 2097152))[i];
    float4 v3 = ((const float4*)(Cpart + 3145728))[i];
    float4 bv = ((const float4*)b2)[i & 127];
    float4 rv = ((const float4*)attnT)[i];
    float4 o;
    o.x = v0.x + v1.x + v2.x + v3.x + bv.x + rv.x;
    o.y = v0.y + v1.y + v2.y + v3.y + bv.y + rv.y;
    o.z = v0.z + v1.z + v2.z + v3.z + bv.z + rv.z;
    o.w = v0.w + v1.w + v2.w + v3.w + bv.w + rv.w;
    ((float4*)Xn)[i] = o;
    ushort4 hv, lv;
    splitf(o.x, hv.x, lv.x);
    splitf(o.y, hv.y, lv.y);
    splitf(o.z, hv.z, lv.z);
    splitf(o.w, hv.w, lv.w);
    ((ushort4*)Xhi)[i] = hv;
    ((ushort4*)Xlo)[i] = lv;
}

__global__ __launch_bounds__(256) void transpose_k(
    const float* __restrict__ src, float* __restrict__ dst, int R, int C)
{
    __shared__ float t[32][33];
    int tx = threadIdx.x & 31, ty = threadIdx.x >> 5;
    int c0 = blockIdx.x * 32, r0 = blockIdx.y * 32;
#pragma unroll
    for (int k = 0; k < 4; k++)
        t[ty + 8 * k][tx] = src[(long)(r0 + ty + 8 * k) * C + c0 + tx];
    __syncthreads();
#pragma unroll
    for (int k = 0; k < 4; k++)
        dst[(long)(c0 + ty + 8 * k) * R + r0 + tx] = t[tx][ty + 8 * k];
}

// ---------------------------------------------------------------------------
// Workspace layout identical to prior rounds (~87 MB < proven 94.4 MB).
// ---------------------------------------------------------------------------
extern "C" void kernel_launch(void* const* d_in, const int* in_sizes, int n_in,
                              void* d_out, int out_size, void* d_ws, size_t ws_size,
                              hipStream_t stream)
{
    const float* X0 = (const float*)d_in[0];
    const float* Kw = (const float*)d_in[1];
    const float* Vw = (const float*)d_in[2];
    const float* W1 = (const float*)d_in[3];
    const float* b1 = (const float*)d_in[4];
    const float* W2 = (const float*)d_in[5];
    const float* b2 = (const float*)d_in[6];
    float* out = (float*)d_out;

    float* R0    = (float*)d_ws;
    float* Yt    = R0;                       // 4,194,304  [H,NN,DD] fp32
    u16*   ff1hi = (u16*)(R0 + 4194304);
    u16*   ff1lo = (u16*)(R0 + 6291456);
    float* Cpart = R0 + 8388608;             // 4,194,304
    float* attnT = R0 + 12582912;            // 1,048,576

    float* ext = R0 + 13631488;
    u16* KXThi = (u16*)ext;                  // 262,144 words
    u16* KXTlo = (u16*)(ext + 262144);
    float* XbufA = ext + 524288;             // 1,048,576
    float* XbufB = ext + 1572864;            // 1,048,576
    u16* Xhi  = (u16*)(ext + 2621440);       // 524,288 words
    u16* Xlo  = (u16*)(ext + 3145728);
    u16* athi = (u16*)(ext + 3670016);
    u16* atlo = (u16*)(ext + 4194304);
    u16* Khi  = (u16*)(ext + 4718592);       // 65,536 words
    u16* Klo  = (u16*)(ext + 4784128);
    u16* Vhi  = (u16*)(ext + 4849664);       // 524,288 words
    u16* Vlo  = (u16*)(ext + 5373952);
    u16* W1hi = (u16*)(ext + 5898240);
    u16* W1lo = (u16*)(ext + 6422528);
    u16* W2hi = (u16*)(ext + 6946816);
    u16* W2lo = (u16*)(ext + 7471104);
    float* wrecip = ext + 7995392;           // 8,192
    unsigned int* entries = (unsigned int*)(ext + 8003584);  // 131,072
    unsigned int* csr     = (unsigned int*)(ext + 8134656);  // 131,072
    int* colOff   = (int*)(ext + 8265728);   // 2,112
    int* counters = (int*)(ext + 8267840);   // 64
    unsigned* rowmaxU = (unsigned*)(ext + 8267904);  // 8,192
    int* rowcnt   = (int*)(ext + 8276096);   // 8,192 (adjacent to rowmaxU)

    zero_k<<<1, 64, 0, stream>>>(counters);

    // XT0 = X0^T [N, D]; split to bf16 hi/lo
    transpose_k<<<dim3(NN / 32, DD / 32), 256, 0, stream>>>(X0, XbufA, DD, NN);
    split_k<<<dim3(1024), 256, 0, stream>>>(XbufA, Xhi, Xlo);

    float* Xc = XbufA;
    for (int li = 0; li < LL; li++) {
        float* Xn = (li & 1) ? XbufA : XbufB;

        // 0) split this layer's weights to bf16 hi/lo
        splitw_k<<<dim3(3200), 256, 0, stream>>>(
            Kw + (long)li * 131072, Vw + (long)li * 1048576,
            W1 + (long)li * 1048576, W2 + (long)li * 1048576,
            Khi, Klo, Vhi, Vlo, W1hi, W1lo, W2hi, W2lo);

        // 1) KXT = XT @ Kw^T  [2048, 256], K=512 -> hi/lo. MI=1: 128 blocks.
        mgemm_k<1, 0, 0, 0, 1><<<dim3(2, 64, 1), 256, 0, stream>>>(
            Xhi, Xlo, Khi, Klo, nullptr, KXThi, KXTlo, nullptr,
            NN, HH * QQ, DD, DD, DD, HH * QQ, 0, 0, 0);

        // 2) fused mask path: no S materialization
        initrow_k<<<dim3(64), 256, 0, stream>>>(rowmaxU);   // zeroes rowcnt too
        smax_k<<<dim3(16, 16, HH), 256, 0, stream>>>(KXThi, KXTlo, rowmaxU);
        sextract_k<<<dim3(16, 16, HH), 256, 0, stream>>>(
            KXThi, KXTlo, rowmaxU, rowcnt, entries, counters + li);
        wrecip_k<<<dim3(32), 256, 0, stream>>>(rowmaxU, rowcnt, wrecip);
        buildcsr_k<<<dim3(1), 256, 0, stream>>>(entries, counters + li, csr, colOff);

        // 4) Yt_h = XT @ V_h^T  [NN, DD] fp32, batch H. MI=4: 256 blocks.
        mgemm_k<4, 0, 0, 1, 0><<<dim3(4, 16, HH), 256, 0, stream>>>(
            Xhi, Xlo, Vhi, Vlo, Yt, nullptr, nullptr, nullptr,
            NN, DD, DD, DD, DD, DD, 0, (long)DD * DD, (long)NN * DD);

        // 5) attnT = XT + sparse combine; then split for FF1 input
        initattn_k<<<dim3(NN * DD / 4 / 256), 256, 0, stream>>>(Xc, attnT);
        apply_k<<<dim3(APPLY_BLOCKS), 256, 0, stream>>>(csr, colOff, wrecip, Yt, attnT);
        split_k<<<dim3(1024), 256, 0, stream>>>(attnT, athi, atlo);

        // 6) ff1 = relu(attnT @ W1^T + b1)  [NN, DFF] -> hi/lo. MI=4: 256 blk.
        mgemm_k<4, 1, 1, 0, 1><<<dim3(16, 16, 1), 256, 0, stream>>>(
            athi, atlo, W1hi, W1lo, nullptr, ff1hi, ff1lo,
            b1 + (long)li * DFFC,
            NN, DFFC, DD, DD, DD, DFFC, 0, 0, 0);

        // 7) FF2 split-K=4, MI=4: 256 blocks.
        mgemm_k<4, 0, 0, 1, 0><<<dim3(4, 16, 4), 256, 0, stream>>>(
            ff1hi, ff1lo, W2hi, W2lo, Cpart, nullptr, nullptr, nullptr,
            NN, DD, 512, DFFC, DFFC, DD, 512, 512, (long)NN * DD);
        ff2red_k<<<dim3(1024), 256, 0, stream>>>(
            Cpart, b2 + (long)li * DD, attnT, Xn, Xhi, Xlo);

        Xc = Xn;
    }

    // out = XT_final^T  [D, N]
    transpose_k<<<dim3(DD / 32, NN / 32), 256, 0, stream>>>(Xc, out, NN, DD);
}

// Round 2
// 1435.977 us; speedup vs baseline: 1.3729x; 1.1152x over previous
//
#include <hip/hip_runtime.h>

// Problem constants
#define LL   8
#define HH   4
#define QQ   64
#define DD   512
#define NN   2048
#define DFFC 2048
#define ENTRY_CAP (1 << 17)
#define CHUNK 8
#define APPLY_BLOCKS 2048
#define LCAP 2048   // per-block LDS entry staging capacity

typedef short     bf16x8 __attribute__((ext_vector_type(8)));  // 8 bf16 = 4 VGPR
typedef float     f32x4  __attribute__((ext_vector_type(4)));  // MFMA C/D frag
typedef unsigned short u16;

// fp32 -> (hi, lo) bf16 split, RNE. x ~= hi + lo with ~16-bit mantissa coverage.
__device__ inline void splitf(float v, u16& h, u16& l)
{
    unsigned u  = __float_as_uint(v);
    unsigned uh = u + (0x7FFFu + ((u >> 16) & 1u));
    h = (u16)(uh >> 16);
    float fh = __uint_as_float(((unsigned)h) << 16);
    float r  = v - fh;
    unsigned ur = __float_as_uint(r);
    unsigned ul = ur + (0x7FFFu + ((ur >> 16) & 1u));
    l = (u16)(ul >> 16);
}

// Monotone fp32 <-> uint mapping for atomicMax on floats (no NaNs in data).
__device__ inline unsigned mapf(float f)
{
    unsigned u = __float_as_uint(f);
    return (u >> 31) ? ~u : (u | 0x80000000u);
}
__device__ inline float unmapf(unsigned u)
{
    return (u >> 31) ? __uint_as_float(u ^ 0x80000000u) : __uint_as_float(~u);
}

// ---------------------------------------------------------------------------
// 8-wave split-bf16 MFMA GEMM (NT): C[M,N] = A[M,K] @ B[N,K]^T as
// hi*hi + hi*lo + lo*hi (fp32 accumulate). 512 thr = 8 waves (4 wy x 2 wx),
// tile 128x128, BK=32, double-buffered 2x32KB LDS via global_load_lds w=16.
// 2 waves/SIMD at 1 block/CU -> stage latency + barrier drains overlap with
// the co-resident wave's MFMA (m114 mechanism); round-1's 4-wave version had
// 1 wave/SIMD and fully exposed every stall (~25us vs ~5us floor).
// XCD-aware swizzle: per-z grid chunked so each XCD's L2 holds its A-band.
// K mult of 32; M mult of 128; N mult of 128; all grids (gx*gy)%8==0.
// ---------------------------------------------------------------------------
template <int BIAS, int RELU, int WF32, int WSPLIT>
__global__ __launch_bounds__(512, 2) void mgemm8_k(
    const u16* __restrict__ Ahi, const u16* __restrict__ Alo,
    const u16* __restrict__ Bhi, const u16* __restrict__ Blo,
    float* __restrict__ C, u16* __restrict__ Chi, u16* __restrict__ Clo,
    const float* __restrict__ bias,
    int K, int lda, int ldb, int ldc,
    long sAoff, long sBoff, long sCoff)
{
    __shared__ __align__(16) u16 smem[2 * 2048 * 8];   // 64 KB

    const int bz = blockIdx.z;
    Ahi += bz * sAoff;  Alo += bz * sAoff;
    Bhi += bz * sBoff;  Blo += bz * sBoff;
    const long cOff = (long)bz * sCoff;

    // XCD swizzle of the per-z 2D grid (nwg % 8 == 0 at every call site)
    const int gx = gridDim.x, nwg = gx * gridDim.y;
    int lin = blockIdx.y * gx + blockIdx.x;
    lin = (lin & 7) * (nwg >> 3) + (lin >> 3);
    const int bx = lin % gx, by = lin / gx;

    const int tid  = threadIdx.x;
    const int lane = tid & 63;
    const int wave = tid >> 6;
    const int quad = lane >> 4, l15 = lane & 15;
    const int wy = wave >> 1, wx = wave & 1;
    const long mTile = (long)by * 128;
    const long nTile = (long)bx * 128;

    // fragment-read chunk swizzle (row bits 0..3 == l15 for all frag rows)
    const int fsw = (l15 & 3) ^ ((l15 >> 2) & 3);
    const int cA  = (quad ^ fsw) * 8;              // u16 offset of 16B chunk

    // staging: 512 thr cover one 512-chunk stream per instruction.
    // LDS dest linear (wave-uniform base + lane*16B); global source carries
    // the inverse swizzle (chunk c holds global chunk c ^ f(row)).
    const int sr = tid >> 2;                                   // row 0..127
    const int sc = (tid & 3) ^ ((sr & 3) ^ ((sr >> 2) & 3));   // src chunk
    const long aoff = (mTile + sr) * (long)lda + sc * 8;
    const long boff = (nTile + sr) * (long)ldb + sc * 8;

#define STAGE8(bufi, koff)                                                    \
    {                                                                         \
        u16* lb = (u16*)smem + (bufi) * (2048 * 8) + tid * 8;                 \
        __builtin_amdgcn_global_load_lds(                                     \
            (const __attribute__((address_space(1))) void*)(Ahi + aoff + (koff)), \
            (__attribute__((address_space(3))) void*)(lb), 16, 0, 0);         \
        __builtin_amdgcn_global_load_lds(                                     \
            (const __attribute__((address_space(1))) void*)(Alo + aoff + (koff)), \
            (__attribute__((address_space(3))) void*)(lb + 512 * 8), 16, 0, 0); \
        __builtin_amdgcn_global_load_lds(                                     \
            (const __attribute__((address_space(1))) void*)(Bhi + boff + (koff)), \
            (__attribute__((address_space(3))) void*)(lb + 1024 * 8), 16, 0, 0); \
        __builtin_amdgcn_global_load_lds(                                     \
            (const __attribute__((address_space(1))) void*)(Blo + boff + (koff)), \
            (__attribute__((address_space(3))) void*)(lb + 1536 * 8), 16, 0, 0); \
    }

    f32x4 acc[2][4];
#pragma unroll
    for (int i = 0; i < 2; i++)
#pragma unroll
        for (int j = 0; j < 4; j++)
            acc[i][j] = (f32x4){0.f, 0.f, 0.f, 0.f};

    STAGE8(0, 0)
    int buf = 0;
    const int NT = K >> 5;
    for (int t = 0; t < NT; t++) {
        __syncthreads();                 // buf staged (vmcnt drain) + prev reads done
        if (t + 1 < NT) STAGE8(buf ^ 1, (t + 1) << 5)

        const u16* Lb = (const u16*)smem + buf * (2048 * 8);
        bf16x8 ah[2], al[2], bh[4], bl[4];
#pragma unroll
        for (int i = 0; i < 2; i++) {
            const int off = (wy * 32 + i * 16 + l15) * 32 + cA;
            ah[i] = *(const bf16x8*)(Lb + off);
            al[i] = *(const bf16x8*)(Lb + 512 * 8 + off);
        }
#pragma unroll
        for (int j = 0; j < 4; j++) {
            const int off = (wx * 64 + j * 16 + l15) * 32 + cA;
            bh[j] = *(const bf16x8*)(Lb + 1024 * 8 + off);
            bl[j] = *(const bf16x8*)(Lb + 1536 * 8 + off);
        }

#pragma unroll
        for (int i = 0; i < 2; i++)
#pragma unroll
            for (int j = 0; j < 4; j++) {
                acc[i][j] = __builtin_amdgcn_mfma_f32_16x16x32_bf16(
                    ah[i], bh[j], acc[i][j], 0, 0, 0);
                acc[i][j] = __builtin_amdgcn_mfma_f32_16x16x32_bf16(
                    ah[i], bl[j], acc[i][j], 0, 0, 0);
                acc[i][j] = __builtin_amdgcn_mfma_f32_16x16x32_bf16(
                    al[i], bh[j], acc[i][j], 0, 0, 0);
            }
        buf ^= 1;
    }
#undef STAGE8

    const int mBase = (int)mTile + wy * 32;
    const int nBase = (int)nTile + wx * 64;
#pragma unroll
    for (int i = 0; i < 2; i++) {
#pragma unroll
        for (int j = 0; j < 4; j++) {
            const int n = nBase + j * 16 + l15;
            const float bv = BIAS ? bias[n] : 0.0f;
#pragma unroll
            for (int r = 0; r < 4; r++) {
                const int m = mBase + i * 16 + quad * 4 + r;
                float v = acc[i][j][r] + bv;
                if (RELU) v = fmaxf(v, 0.0f);
                const long o = cOff + (long)m * ldc + n;
                if (WF32) C[o] = v;
                if (WSPLIT) {
                    u16 h, l;
                    splitf(v, h, l);
                    Chi[o] = h;
                    Clo[o] = l;
                }
            }
        }
    }
}

// ---------------------------------------------------------------------------
// 4-wave split-bf16 GEMM (kept for KXT, MI=1: tile 32x128). Round-1 LDS
// structure + XCD swizzle added.
// ---------------------------------------------------------------------------
template <int MI, int BIAS, int RELU, int WF32, int WSPLIT>
__global__ __launch_bounds__(256, 2) void mgemm_k(
    const u16* __restrict__ Ahi, const u16* __restrict__ Alo,
    const u16* __restrict__ Bhi, const u16* __restrict__ Blo,
    float* __restrict__ C, u16* __restrict__ Chi, u16* __restrict__ Clo,
    const float* __restrict__ bias,
    int M, int N, int K, int lda, int ldb, int ldc,
    long sAoff, long sBoff, long sCoff)
{
    constexpr int ACH = MI * 128;        // 16B chunks per A stream per BK-tile
    constexpr int TOT = 2 * ACH + 1024;  // chunks per buffer (Ahi|Alo|Bhi|Blo)
    __shared__ __align__(16) u16 smem[2 * TOT * 8];

    const int bz = blockIdx.z;
    Ahi += bz * sAoff;  Alo += bz * sAoff;
    Bhi += bz * sBoff;  Blo += bz * sBoff;
    const long cOff = (long)bz * sCoff;

    const int gx = gridDim.x, nwg = gx * gridDim.y;
    int lin = blockIdx.y * gx + blockIdx.x;
    lin = (lin & 7) * (nwg >> 3) + (lin >> 3);
    const int bxs = lin % gx, bys = lin / gx;

    const int tid  = threadIdx.x;
    const int wave = tid >> 6, lane = tid & 63;
    const int quad = lane >> 4, l15 = lane & 15;
    const int wy = wave >> 1, wx = wave & 1;
    const long mTile = (long)bys * (MI * 32);
    const long nTile = (long)bxs * 128;
    const int mBase = (int)mTile + wy * (MI * 16);
    const int nBase = (int)nTile + wx * 64;

    const int fsw = (l15 & 3) ^ ((l15 >> 2) & 3);
    const int cA  = (quad ^ fsw) * 8;

#define STAGE(bufi, koff)                                                     \
    {                                                                         \
        _Pragma("unroll")                                                     \
        for (int s = 0; s < TOT / 256; s++) {                                 \
            const int idx = s * 256 + tid;                                    \
            const u16* sp;  long rowb;  int ldx;  int rel;                    \
            if (idx < ACH)                { sp = Ahi; rel = idx;               rowb = 0; ldx = lda; } \
            else if (idx < 2 * ACH)       { sp = Alo; rel = idx - ACH;         rowb = 0; ldx = lda; } \
            else if (idx < 2 * ACH + 512) { sp = Bhi; rel = idx - 2 * ACH;     rowb = 1; ldx = ldb; } \
            else                          { sp = Blo; rel = idx - 2*ACH - 512; rowb = 1; ldx = ldb; } \
            const long rb = rowb ? nTile : mTile;                             \
            const int r = rel >> 2;                                           \
            const int c = (rel & 3) ^ ((r & 3) ^ ((r >> 2) & 3));             \
            const u16* g = sp + (rb + r) * (long)ldx + (koff) + c * 8;        \
            u16* lp = (u16*)smem + (bufi) * (TOT * 8) + idx * 8;              \
            __builtin_amdgcn_global_load_lds(                                 \
                (const __attribute__((address_space(1))) void*)g,             \
                (__attribute__((address_space(3))) void*)lp, 16, 0, 0);       \
        }                                                                     \
    }

    f32x4 acc[MI][4];
#pragma unroll
    for (int i = 0; i < MI; i++)
#pragma unroll
        for (int j = 0; j < 4; j++)
            acc[i][j] = (f32x4){0.f, 0.f, 0.f, 0.f};

    STAGE(0, 0)
    int buf = 0;
    const int NT = K >> 5;
    for (int t = 0; t < NT; t++) {
        __syncthreads();
        if (t + 1 < NT) STAGE(buf ^ 1, (t + 1) << 5)

        const u16* Lb = (const u16*)smem + buf * (TOT * 8);
        bf16x8 ah[MI], al[MI], bh[4], bl[4];
#pragma unroll
        for (int i = 0; i < MI; i++) {
            const int off = (wy * (MI * 16) + i * 16 + l15) * 32 + cA;
            ah[i] = *(const bf16x8*)(Lb + off);
            al[i] = *(const bf16x8*)(Lb + ACH * 8 + off);
        }
#pragma unroll
        for (int j = 0; j < 4; j++) {
            const int off = (wx * 64 + j * 16 + l15) * 32 + cA;
            bh[j] = *(const bf16x8*)(Lb + 2 * ACH * 8 + off);
            bl[j] = *(const bf16x8*)(Lb + 2 * ACH * 8 + 512 * 8 + off);
        }

#pragma unroll
        for (int i = 0; i < MI; i++)
#pragma unroll
            for (int j = 0; j < 4; j++) {
                acc[i][j] = __builtin_amdgcn_mfma_f32_16x16x32_bf16(
                    ah[i], bh[j], acc[i][j], 0, 0, 0);
                acc[i][j] = __builtin_amdgcn_mfma_f32_16x16x32_bf16(
                    ah[i], bl[j], acc[i][j], 0, 0, 0);
                acc[i][j] = __builtin_amdgcn_mfma_f32_16x16x32_bf16(
                    al[i], bh[j], acc[i][j], 0, 0, 0);
            }
        buf ^= 1;
    }
#undef STAGE

#pragma unroll
    for (int i = 0; i < MI; i++) {
#pragma unroll
        for (int j = 0; j < 4; j++) {
            const int n = nBase + j * 16 + l15;
            const float bv = BIAS ? bias[n] : 0.0f;
#pragma unroll
            for (int r = 0; r < 4; r++) {
                const int m = mBase + i * 16 + quad * 4 + r;
                float v = acc[i][j][r] + bv;
                if (RELU) v = fmaxf(v, 0.0f);
                const long o = cOff + (long)m * ldc + n;
                if (WF32) C[o] = v;
                if (WSPLIT) {
                    u16 h, l;
                    splitf(v, h, l);
                    Chi[o] = h;
                    Clo[o] = l;
                }
            }
        }
    }
}

// ---------------------------------------------------------------------------
// Fused mask path, pass A: per-head Gram tile S = G G^T; NEW: one-shot LDS
// staging of all 4 streams (halves L2 traffic: rows shared by wave pairs are
// read once). MFMA order (s{i{j{hh,hl,lh}}}) IDENTICAL to sextract_k ->
// same bits for the threshold compare. XOR chunk swizzle both-sides.
// ---------------------------------------------------------------------------
__global__ __launch_bounds__(256, 2) void smax_k(
    const u16* __restrict__ Ghi, const u16* __restrict__ Glo,
    unsigned* __restrict__ rowmaxU)
{
    __shared__ __align__(16) u16 gs[4096 * 8];   // 64 KB: Ahi|Alo|Bhi|Blo
    const int h = blockIdx.z;
    const int lda = HH * QQ;
    const u16* Gh = Ghi + h * QQ;
    const u16* Gl = Glo + h * QQ;

    const int gx = gridDim.x, nwg = gx * gridDim.y;   // 16, 256
    int lin = blockIdx.y * gx + blockIdx.x;
    lin = (lin & 7) * (nwg >> 3) + (lin >> 3);
    const int bxs = lin % gx, bys = lin / gx;

    const int tid  = threadIdx.x;
    const int wave = tid >> 6, lane = tid & 63;
    const int quad = lane >> 4, l15 = lane & 15;
    const int wy = wave >> 1, wx = wave & 1;
    const int rT = bys * 128, cT = bxs * 128;
    const int rB = rT + wy * 64;
    const int cB = cT + wx * 64;

    // stage: 4 streams x 1024 chunks (128 rows x 8), 16 loads/thread.
#define SSTG(src, rowbase, dstbase)                                           \
    _Pragma("unroll")                                                         \
    for (int it = 0; it < 4; it++) {                                          \
        const int idx = it * 256 + tid;                                       \
        const int r = idx >> 3;                                               \
        const int c = (idx & 7) ^ (r & 7);                                    \
        __builtin_amdgcn_global_load_lds(                                     \
            (const __attribute__((address_space(1))) void*)(src + (long)((rowbase) + r) * lda + c * 8), \
            (__attribute__((address_space(3))) void*)((u16*)gs + (dstbase) + idx * 8), 16, 0, 0); \
    }
    SSTG(Gh, rT, 0)
    SSTG(Gl, rT, 8192)
    SSTG(Gh, cT, 16384)
    SSTG(Gl, cT, 24576)
#undef SSTG
    __syncthreads();

    bf16x8 ah[2][4], al[2][4], bh[2][4], bl[2][4];
#pragma unroll
    for (int s = 0; s < 2; s++) {
#pragma unroll
        for (int i = 0; i < 4; i++) {
            const int ra = wy * 64 + i * 16 + l15;
            const int ca = ((s * 4 + quad) ^ (ra & 7)) * 8;
            ah[s][i] = *(const bf16x8*)(gs + ra * 64 + ca);
            al[s][i] = *(const bf16x8*)(gs + 8192 + ra * 64 + ca);
            const int rb = wx * 64 + i * 16 + l15;
            const int cb = ((s * 4 + quad) ^ (rb & 7)) * 8;
            bh[s][i] = *(const bf16x8*)(gs + 16384 + rb * 64 + cb);
            bl[s][i] = *(const bf16x8*)(gs + 24576 + rb * 64 + cb);
        }
    }

    f32x4 acc[4][4];
#pragma unroll
    for (int i = 0; i < 4; i++)
#pragma unroll
        for (int j = 0; j < 4; j++)
            acc[i][j] = (f32x4){0.f, 0.f, 0.f, 0.f};

#pragma unroll
    for (int s = 0; s < 2; s++)
#pragma unroll
        for (int i = 0; i < 4; i++)
#pragma unroll
            for (int j = 0; j < 4; j++) {
                acc[i][j] = __builtin_amdgcn_mfma_f32_16x16x32_bf16(ah[s][i], bh[s][j], acc[i][j], 0, 0, 0);
                acc[i][j] = __builtin_amdgcn_mfma_f32_16x16x32_bf16(ah[s][i], bl[s][j], acc[i][j], 0, 0, 0);
                acc[i][j] = __builtin_amdgcn_mfma_f32_16x16x32_bf16(al[s][i], bh[s][j], acc[i][j], 0, 0, 0);
            }

#pragma unroll
    for (int i = 0; i < 4; i++)
#pragma unroll
        for (int r = 0; r < 4; r++) {
            float mx = acc[i][0][r];
#pragma unroll
            for (int j = 1; j < 4; j++) mx = fmaxf(mx, acc[i][j][r]);
#pragma unroll
            for (int off = 1; off < 16; off <<= 1)
                mx = fmaxf(mx, __shfl_xor(mx, off, 64));
            if (l15 == 0)
                atomicMax(&rowmaxU[h * NN + rB + i * 16 + quad * 4 + r], mapf(mx));
        }
}

// ---------------------------------------------------------------------------
// Fused mask path, pass B: recompute IDENTICAL S tile (same per-(s,i,j) MFMA
// order and fragment values as smax -> same bits), threshold, count, emit.
// Structure kept from the passing round-1 kernel; only the XCD swizzle added
// (block->tile remap only; per-tile work identical).
// ---------------------------------------------------------------------------
__global__ __launch_bounds__(256) void sextract_k(
    const u16* __restrict__ Ghi, const u16* __restrict__ Glo,
    const unsigned* __restrict__ rowmaxU, int* __restrict__ rowcnt,
    unsigned int* __restrict__ entries, int* __restrict__ counter)
{
    const int h = blockIdx.z;
    const u16* Ah = Ghi + h * QQ;
    const u16* Al = Glo + h * QQ;
    const int lda = HH * QQ;

    const int gx = gridDim.x, nwg = gx * gridDim.y;
    int lin = blockIdx.y * gx + blockIdx.x;
    lin = (lin & 7) * (nwg >> 3) + (lin >> 3);
    const int bxs = lin % gx, bys = lin / gx;

    const int tid  = threadIdx.x;
    const int wave = tid >> 6, lane = tid & 63;
    const int quad = lane >> 4, l15 = lane & 15;
    const int wy = wave >> 1, wx = wave & 1;
    const int rB = bys * 128 + wy * 64;
    const int cB = bxs * 128 + wx * 64;

    __shared__ float thrS[128];
    __shared__ unsigned lbuf[LCAP];
    __shared__ int lcnt, gbase;
    if (tid == 0) lcnt = 0;
    if (tid < 128) {
        float mx = unmapf(rowmaxU[h * NN + bys * 128 + tid]);
        thrS[tid] = (fabsf(mx) > 0.5f) ? mx - 0.5f : 3.402823466e38f;
    }
    __syncthreads();

    bf16x8 ah[2][4], al[2][4], bh[2][4], bl[2][4];
#pragma unroll
    for (int s = 0; s < 2; s++) {
        const int kk = s * 32 + quad * 8;
#pragma unroll
        for (int i = 0; i < 4; i++) {
            long ar = (long)(rB + i * 16 + l15) * lda + kk;
            ah[s][i] = *(const bf16x8*)(Ah + ar);
            al[s][i] = *(const bf16x8*)(Al + ar);
            long br = (long)(cB + i * 16 + l15) * lda + kk;
            bh[s][i] = *(const bf16x8*)(Ah + br);
            bl[s][i] = *(const bf16x8*)(Al + br);
        }
    }

    f32x4 acc[4][4];
#pragma unroll
    for (int i = 0; i < 4; i++)
#pragma unroll
        for (int j = 0; j < 4; j++)
            acc[i][j] = (f32x4){0.f, 0.f, 0.f, 0.f};

#pragma unroll
    for (int s = 0; s < 2; s++)
#pragma unroll
        for (int i = 0; i < 4; i++)
#pragma unroll
            for (int j = 0; j < 4; j++) {
                acc[i][j] = __builtin_amdgcn_mfma_f32_16x16x32_bf16(ah[s][i], bh[s][j], acc[i][j], 0, 0, 0);
                acc[i][j] = __builtin_amdgcn_mfma_f32_16x16x32_bf16(ah[s][i], bl[s][j], acc[i][j], 0, 0, 0);
                acc[i][j] = __builtin_amdgcn_mfma_f32_16x16x32_bf16(al[s][i], bh[s][j], acc[i][j], 0, 0, 0);
            }

#pragma unroll
    for (int i = 0; i < 4; i++) {
#pragma unroll
        for (int r = 0; r < 4; r++) {
            const int lr  = wy * 64 + i * 16 + quad * 4 + r;
            const int row = h * NN + rB + i * 16 + quad * 4 + r;
            const float thr = thrS[lr];

            int c = 0;
#pragma unroll
            for (int j = 0; j < 4; j++) c += (acc[i][j][r] >= thr) ? 1 : 0;
            int cs = c;
#pragma unroll
            for (int off = 1; off < 16; off <<= 1) cs += __shfl_xor(cs, off, 64);
            if (l15 == 0 && cs > 0) atomicAdd(&rowcnt[row], cs);

#pragma unroll
            for (int j = 0; j < 4; j++) {
                if (acc[i][j][r] >= thr) {
                    unsigned ent = ((unsigned)row << 11) |
                                   (unsigned)(cB + j * 16 + l15);
                    int s2 = atomicAdd(&lcnt, 1);
                    if (s2 < LCAP) {
                        lbuf[s2] = ent;
                    } else {
                        unsigned p = (unsigned)atomicAdd(counter, 1);
                        if (p < ENTRY_CAP) entries[p] = ent;
                    }
                }
            }
        }
    }

    __syncthreads();
    int n = lcnt;
    if (n > LCAP) n = LCAP;
    if (n > 0) {
        if (tid == 0) gbase = atomicAdd(counter, n);
        __syncthreads();
        for (int i2 = tid; i2 < n; i2 += 256) {
            unsigned p = (unsigned)(gbase + i2);
            if (p < ENTRY_CAP) entries[p] = lbuf[i2];
        }
    }
}

// ---------------------------------------------------------------------------
// split / splitw(+rowmax zero) / splitc(+attnT copy) / zero / buildcsr /
// apply(inline wrecip) / ff2red(+attnT writeback) / transpose
// ---------------------------------------------------------------------------
__global__ __launch_bounds__(256) void split_k(
    const float* __restrict__ src, u16* __restrict__ hi, u16* __restrict__ lo)
{
    int i = blockIdx.x * 256 + threadIdx.x;
    float4 v = ((const float4*)src)[i];
    ushort4 hv, lv;
    splitf(v.x, hv.x, lv.x);
    splitf(v.y, hv.y, lv.y);
    splitf(v.z, hv.z, lv.z);
    splitf(v.w, hv.w, lv.w);
    ((ushort4*)hi)[i] = hv;
    ((ushort4*)lo)[i] = lv;
}

// initial split that also seeds attnT = X^T (replaces initattn for layer 0)
__global__ __launch_bounds__(256) void splitc_k(
    const float* __restrict__ src, u16* __restrict__ hi, u16* __restrict__ lo,
    float* __restrict__ cpy)
{
    int i = blockIdx.x * 256 + threadIdx.x;
    float4 v = ((const float4*)src)[i];
    ((float4*)cpy)[i] = v;
    ushort4 hv, lv;
    splitf(v.x, hv.x, lv.x);
    splitf(v.y, hv.y, lv.y);
    splitf(v.z, hv.z, lv.z);
    splitf(v.w, hv.w, lv.w);
    ((ushort4*)hi)[i] = hv;
    ((ushort4*)lo)[i] = lv;
}

__global__ __launch_bounds__(256) void splitw_k(
    const float* __restrict__ K_, const float* __restrict__ V_,
    const float* __restrict__ W1_, const float* __restrict__ W2_,
    u16* __restrict__ Khi, u16* __restrict__ Klo,
    u16* __restrict__ Vhi, u16* __restrict__ Vlo,
    u16* __restrict__ W1hi, u16* __restrict__ W1lo,
    u16* __restrict__ W2hi, u16* __restrict__ W2lo,
    unsigned* __restrict__ zrow)
{
    int i = blockIdx.x * 256 + threadIdx.x;
    if (i < 16384) zrow[i] = 0u;      // zero rowmaxU + rowcnt (contiguous)
    const float* s;
    u16 *h, *l;
    int off;
    if (i < 32768)       { s = K_;  h = Khi;  l = Klo;  off = i; }
    else if (i < 294912) { s = V_;  h = Vhi;  l = Vlo;  off = i - 32768; }
    else if (i < 557056) { s = W1_; h = W1hi; l = W1lo; off = i - 294912; }
    else                 { s = W2_; h = W2hi; l = W2lo; off = i - 557056; }
    float4 v = ((const float4*)s)[off];
    ushort4 hv, lv;
    splitf(v.x, hv.x, lv.x);
    splitf(v.y, hv.y, lv.y);
    splitf(v.z, hv.z, lv.z);
    splitf(v.w, hv.w, lv.w);
    ((ushort4*)h)[off] = hv;
    ((ushort4*)l)[off] = lv;
}

__global__ void zero_k(int* __restrict__ counters)
{
    if (threadIdx.x < LL) counters[threadIdx.x] = 0;
}

__global__ __launch_bounds__(256) void buildcsr_k(
    const unsigned int* __restrict__ entries, const int* __restrict__ counter,
    unsigned int* __restrict__ csr, int* __restrict__ colOff)
{
    __shared__ int hist[NN];
    __shared__ int part[256];
    const int t = threadIdx.x;
    int cnt = *counter;
    if (cnt > ENTRY_CAP) cnt = ENTRY_CAP;

    for (int i = t; i < NN; i += 256) hist[i] = 0;
    __syncthreads();
    for (int i = t; i < cnt; i += 256)
        atomicAdd(&hist[entries[i] & 2047], 1);
    __syncthreads();

    int e[8];
    int s = 0;
#pragma unroll
    for (int i = 0; i < 8; i++) { e[i] = s; s += hist[t * 8 + i]; }
    part[t] = s;
    __syncthreads();
    for (int off = 1; off < 256; off <<= 1) {
        int x = (t >= off) ? part[t - off] : 0;
        __syncthreads();
        part[t] += x;
        __syncthreads();
    }
    int base = (t > 0) ? part[t - 1] : 0;
    int my[8];
#pragma unroll
    for (int i = 0; i < 8; i++) my[i] = base + e[i];
#pragma unroll
    for (int i = 0; i < 8; i++) colOff[t * 8 + i] = my[i];
    if (t == 255) colOff[NN] = part[255];
    __syncthreads();
#pragma unroll
    for (int i = 0; i < 8; i++) hist[t * 8 + i] = my[i];
    __syncthreads();

    for (int i = t; i < cnt; i += 256) {
        unsigned v = entries[i];
        int slot = atomicAdd(&hist[v & 2047], 1);
        csr[slot] = v;
    }
}

__global__ __launch_bounds__(256) void apply_k(
    const unsigned int* __restrict__ csr, const int* __restrict__ colOff,
    const unsigned* __restrict__ rowmaxU, const int* __restrict__ rowcnt,
    const float* __restrict__ Yt, float* __restrict__ attnT)
{
    const int total = colOff[NN];
    const int tid = threadIdx.x;

    for (int base = blockIdx.x * CHUNK; base < total;
         base += gridDim.x * CHUNK) {
        int end = base + CHUNK;
        if (end > total) end = total;

        float a0 = 0.0f, a1 = 0.0f;
        int curM = -1;
        for (int e = base; e < end; e++) {
            unsigned v = csr[e];
            int m = v & 2047;
            int row = (int)(v >> 11);
            if (m != curM) {
                if (curM >= 0) {
                    atomicAdd(&attnT[(long)curM * DD + tid], a0);
                    atomicAdd(&attnT[(long)curM * DD + tid + 256], a1);
                }
                curM = m;
                a0 = a1 = 0.0f;
            }
            float mx = unmapf(rowmaxU[row]);
            float w = (fabsf(mx) > 0.5f)
                          ? 1.0f / fmaxf((float)rowcnt[row], 1.0f) : 0.0f;
            const float* y = Yt + (long)row * DD;
            a0 += w * y[tid];
            a1 += w * y[tid + 256];
        }
        if (curM >= 0) {
            atomicAdd(&attnT[(long)curM * DD + tid], a0);
            atomicAdd(&attnT[(long)curM * DD + tid + 256], a1);
        }
    }
}

__global__ __launch_bounds__(256) void ff2red_k(
    const float* __restrict__ Cpart, const float* __restrict__ b2,
    float* __restrict__ attnT, float* __restrict__ Xn,
    u16* __restrict__ Xhi, u16* __restrict__ Xlo)
{
    int i = blockIdx.x * 256 + threadIdx.x;
    float4 v0 = ((const float4*)(Cpart))[i];
    float4 v1 = ((const float4*)(Cpart + 1048576))[i];
    float4 v2 = ((const float4*)(Cpart + 2097152))[i];
    float4 v3 = ((const float4*)(Cpart + 3145728))[i];
    float4 bv = ((const float4*)b2)[i & 127];
    float4 rv = ((const float4*)attnT)[i];
    float4 o;
    o.x = v0.x + v1.x + v2.x + v3.x + bv.x + rv.x;
    o.y = v0.y + v1.y + v2.y + v3.y + bv.y + rv.y;
    o.z = v0.z + v1.z + v2.z + v3.z + bv.z + rv.z;
    o.w = v0.w + v1.w + v2.w + v3.w + bv.w + rv.w;
    ((float4*)Xn)[i] = o;
    ((float4*)attnT)[i] = o;           // seed next layer's residual base
    ushort4 hv, lv;
    splitf(o.x, hv.x, lv.x);
    splitf(o.y, hv.y, lv.y);
    splitf(o.z, hv.z, lv.z);
    splitf(o.w, hv.w, lv.w);
    ((ushort4*)Xhi)[i] = hv;
    ((ushort4*)Xlo)[i] = lv;
}

__global__ __launch_bounds__(256) void transpose_k(
    const float* __restrict__ src, float* __restrict__ dst, int R, int C)
{
    __shared__ float t[32][33];
    int tx = threadIdx.x & 31, ty = threadIdx.x >> 5;
    int c0 = blockIdx.x * 32, r0 = blockIdx.y * 32;
#pragma unroll
    for (int k = 0; k < 4; k++)
        t[ty + 8 * k][tx] = src[(long)(r0 + ty + 8 * k) * C + c0 + tx];
    __syncthreads();
#pragma unroll
    for (int k = 0; k < 4; k++)
        dst[(long)(c0 + ty + 8 * k) * R + r0 + tx] = t[tx][ty + 8 * k];
}

// ---------------------------------------------------------------------------
// Workspace layout identical to prior rounds (~87 MB < proven 94.4 MB).
// ---------------------------------------------------------------------------
extern "C" void kernel_launch(void* const* d_in, const int* in_sizes, int n_in,
                              void* d_out, int out_size, void* d_ws, size_t ws_size,
                              hipStream_t stream)
{
    const float* X0 = (const float*)d_in[0];
    const float* Kw = (const float*)d_in[1];
    const float* Vw = (const float*)d_in[2];
    const float* W1 = (const float*)d_in[3];
    const float* b1 = (const float*)d_in[4];
    const float* W2 = (const float*)d_in[5];
    const float* b2 = (const float*)d_in[6];
    float* out = (float*)d_out;

    float* R0    = (float*)d_ws;
    float* Yt    = R0;                       // 4,194,304  [H,NN,DD] fp32
    u16*   ff1hi = (u16*)(R0 + 4194304);
    u16*   ff1lo = (u16*)(R0 + 6291456);
    float* Cpart = R0 + 8388608;             // 4,194,304
    float* attnT = R0 + 12582912;            // 1,048,576

    float* ext = R0 + 13631488;
    u16* KXThi = (u16*)ext;                  // 262,144 words
    u16* KXTlo = (u16*)(ext + 262144);
    float* XbufA = ext + 524288;             // 1,048,576
    float* XbufB = ext + 1572864;            // 1,048,576
    u16* Xhi  = (u16*)(ext + 2621440);       // 524,288 words
    u16* Xlo  = (u16*)(ext + 3145728);
    u16* athi = (u16*)(ext + 3670016);
    u16* atlo = (u16*)(ext + 4194304);
    u16* Khi  = (u16*)(ext + 4718592);       // 65,536 words
    u16* Klo  = (u16*)(ext + 4784128);
    u16* Vhi  = (u16*)(ext + 4849664);       // 524,288 words
    u16* Vlo  = (u16*)(ext + 5373952);
    u16* W1hi = (u16*)(ext + 5898240);
    u16* W1lo = (u16*)(ext + 6422528);
    u16* W2hi = (u16*)(ext + 6946816);
    u16* W2lo = (u16*)(ext + 7471104);
    unsigned int* entries = (unsigned int*)(ext + 8003584);  // 131,072
    unsigned int* csr     = (unsigned int*)(ext + 8134656);  // 131,072
    int* colOff   = (int*)(ext + 8265728);   // 2,112
    int* counters = (int*)(ext + 8267840);   // 64
    unsigned* rowmaxU = (unsigned*)(ext + 8267904);  // 8,192
    int* rowcnt   = (int*)(ext + 8276096);   // 8,192 (contiguous after rowmaxU)

    zero_k<<<1, 64, 0, stream>>>(counters);

    // XT0 = X0^T [N, D]; split to bf16 hi/lo and seed attnT = XT0
    transpose_k<<<dim3(NN / 32, DD / 32), 256, 0, stream>>>(X0, XbufA, DD, NN);
    splitc_k<<<dim3(1024), 256, 0, stream>>>(XbufA, Xhi, Xlo, attnT);

    float* Xc = XbufA;
    for (int li = 0; li < LL; li++) {
        float* Xn = (li & 1) ? XbufA : XbufB;

        // 0) split this layer's weights to bf16 hi/lo (+ zero rowmax/rowcnt)
        splitw_k<<<dim3(3200), 256, 0, stream>>>(
            Kw + (long)li * 131072, Vw + (long)li * 1048576,
            W1 + (long)li * 1048576, W2 + (long)li * 1048576,
            Khi, Klo, Vhi, Vlo, W1hi, W1lo, W2hi, W2lo, rowmaxU);

        // 1) KXT = XT @ Kw^T  [2048, 256], K=512 -> hi/lo. MI=1: 128 blocks.
        mgemm_k<1, 0, 0, 0, 1><<<dim3(2, 64, 1), 256, 0, stream>>>(
            Xhi, Xlo, Khi, Klo, nullptr, KXThi, KXTlo, nullptr,
            NN, HH * QQ, DD, DD, DD, HH * QQ, 0, 0, 0);

        // 2) fused mask path: no S materialization
        smax_k<<<dim3(16, 16, HH), 256, 0, stream>>>(KXThi, KXTlo, rowmaxU);
        sextract_k<<<dim3(16, 16, HH), 256, 0, stream>>>(
            KXThi, KXTlo, rowmaxU, rowcnt, entries, counters + li);
        buildcsr_k<<<dim3(1), 256, 0, stream>>>(entries, counters + li, csr, colOff);

        // 4) Yt_h = XT @ V_h^T  [NN, DD] fp32, batch H. 8-wave: 64 blk/head.
        mgemm8_k<0, 0, 1, 0><<<dim3(4, 16, HH), 512, 0, stream>>>(
            Xhi, Xlo, Vhi, Vlo, Yt, nullptr, nullptr, nullptr,
            DD, DD, DD, DD, 0, (long)DD * DD, (long)NN * DD);

        // 5) attnT (= XT residual, maintained by ff2red/splitc) += sparse combine
        apply_k<<<dim3(APPLY_BLOCKS), 256, 0, stream>>>(
            csr, colOff, rowmaxU, rowcnt, Yt, attnT);
        split_k<<<dim3(1024), 256, 0, stream>>>(attnT, athi, atlo);

        // 6) ff1 = relu(attnT @ W1^T + b1)  [NN, DFF] -> hi/lo. 256 blocks.
        mgemm8_k<1, 1, 0, 1><<<dim3(16, 16, 1), 512, 0, stream>>>(
            athi, atlo, W1hi, W1lo, nullptr, ff1hi, ff1lo,
            b1 + (long)li * DFFC,
            DD, DD, DD, DFFC, 0, 0, 0);

        // 7) FF2 split-K=4: 64 blocks x 4.
        mgemm8_k<0, 0, 1, 0><<<dim3(4, 16, 4), 512, 0, stream>>>(
            ff1hi, ff1lo, W2hi, W2lo, Cpart, nullptr, nullptr, nullptr,
            512, DFFC, DFFC, DD, 512, 512, (long)NN * DD);
        ff2red_k<<<dim3(1024), 256, 0, stream>>>(
            Cpart, b2 + (long)li * DD, attnT, Xn, Xhi, Xlo);

        Xc = Xn;
    }

    // out = XT_final^T  [D, N]
    transpose_k<<<dim3(DD / 32, NN / 32), 256, 0, stream>>>(Xc, out, NN, DD);
}

// Round 3
// 1361.505 us; speedup vs baseline: 1.4479x; 1.0547x over previous
//
#include <hip/hip_runtime.h>

// Problem constants
#define LL   8
#define HH   4
#define QQ   64
#define DD   512
#define NN   2048
#define DFFC 2048
#define ENTRY_CAP (1 << 17)
#define CHUNK 8
#define APPLY_BLOCKS 2048
#define LCAP 2048   // per-block LDS entry staging capacity

typedef short     bf16x8 __attribute__((ext_vector_type(8)));  // 8 bf16 = 4 VGPR
typedef float     f32x4  __attribute__((ext_vector_type(4)));  // MFMA C/D frag
typedef unsigned short u16;

// fp32 -> (hi, lo) bf16 split, RNE. x ~= hi + lo with ~16-bit mantissa coverage.
__device__ inline void splitf(float v, u16& h, u16& l)
{
    unsigned u  = __float_as_uint(v);
    unsigned uh = u + (0x7FFFu + ((u >> 16) & 1u));
    h = (u16)(uh >> 16);
    float fh = __uint_as_float(((unsigned)h) << 16);
    float r  = v - fh;
    unsigned ur = __float_as_uint(r);
    unsigned ul = ur + (0x7FFFu + ((ur >> 16) & 1u));
    l = (u16)(ul >> 16);
}

// Monotone fp32 <-> uint mapping for atomicMax on floats (no NaNs in data).
__device__ inline unsigned mapf(float f)
{
    unsigned u = __float_as_uint(f);
    return (u >> 31) ? ~u : (u | 0x80000000u);
}
__device__ inline float unmapf(unsigned u)
{
    return (u >> 31) ? __uint_as_float(u ^ 0x80000000u) : __uint_as_float(~u);
}

// ---------------------------------------------------------------------------
// 8-wave split-bf16 MFMA GEMM (NT): C[M,N] = A[M,K] @ B[N,K]^T as
// hi*hi + hi*lo + lo*hi (fp32 accumulate). 512 thr = 8 waves (4 wy x 2 wx),
// tile 128x128, BK=32, double-buffered 2x32KB LDS via global_load_lds w=16.
// XCD-aware swizzle for L2 locality. K mult of 32; M,N mult of 128.
// ---------------------------------------------------------------------------
template <int BIAS, int RELU, int WF32, int WSPLIT>
__global__ __launch_bounds__(512, 2) void mgemm8_k(
    const u16* __restrict__ Ahi, const u16* __restrict__ Alo,
    const u16* __restrict__ Bhi, const u16* __restrict__ Blo,
    float* __restrict__ C, u16* __restrict__ Chi, u16* __restrict__ Clo,
    const float* __restrict__ bias,
    int K, int lda, int ldb, int ldc,
    long sAoff, long sBoff, long sCoff)
{
    __shared__ __align__(16) u16 smem[2 * 2048 * 8];   // 64 KB

    const int bz = blockIdx.z;
    Ahi += bz * sAoff;  Alo += bz * sAoff;
    Bhi += bz * sBoff;  Blo += bz * sBoff;
    const long cOff = (long)bz * sCoff;

    // XCD swizzle of the per-z 2D grid (nwg % 8 == 0 at every call site)
    const int gx = gridDim.x, nwg = gx * gridDim.y;
    int lin = blockIdx.y * gx + blockIdx.x;
    lin = (lin & 7) * (nwg >> 3) + (lin >> 3);
    const int bx = lin % gx, by = lin / gx;

    const int tid  = threadIdx.x;
    const int lane = tid & 63;
    const int wave = tid >> 6;
    const int quad = lane >> 4, l15 = lane & 15;
    const int wy = wave >> 1, wx = wave & 1;
    const long mTile = (long)by * 128;
    const long nTile = (long)bx * 128;

    // fragment-read chunk swizzle (row bits 0..3 == l15 for all frag rows)
    const int fsw = (l15 & 3) ^ ((l15 >> 2) & 3);
    const int cA  = (quad ^ fsw) * 8;              // u16 offset of 16B chunk

    // staging: 512 thr cover one 512-chunk stream per instruction.
    // LDS dest linear (wave-uniform base + lane*16B); global source carries
    // the inverse swizzle (chunk c holds global chunk c ^ f(row)).
    const int sr = tid >> 2;                                   // row 0..127
    const int sc = (tid & 3) ^ ((sr & 3) ^ ((sr >> 2) & 3));   // src chunk
    const long aoff = (mTile + sr) * (long)lda + sc * 8;
    const long boff = (nTile + sr) * (long)ldb + sc * 8;

#define STAGE8(bufi, koff)                                                    \
    {                                                                         \
        u16* lb = (u16*)smem + (bufi) * (2048 * 8) + tid * 8;                 \
        __builtin_amdgcn_global_load_lds(                                     \
            (const __attribute__((address_space(1))) void*)(Ahi + aoff + (koff)), \
            (__attribute__((address_space(3))) void*)(lb), 16, 0, 0);         \
        __builtin_amdgcn_global_load_lds(                                     \
            (const __attribute__((address_space(1))) void*)(Alo + aoff + (koff)), \
            (__attribute__((address_space(3))) void*)(lb + 512 * 8), 16, 0, 0); \
        __builtin_amdgcn_global_load_lds(                                     \
            (const __attribute__((address_space(1))) void*)(Bhi + boff + (koff)), \
            (__attribute__((address_space(3))) void*)(lb + 1024 * 8), 16, 0, 0); \
        __builtin_amdgcn_global_load_lds(                                     \
            (const __attribute__((address_space(1))) void*)(Blo + boff + (koff)), \
            (__attribute__((address_space(3))) void*)(lb + 1536 * 8), 16, 0, 0); \
    }

    f32x4 acc[2][4];
#pragma unroll
    for (int i = 0; i < 2; i++)
#pragma unroll
        for (int j = 0; j < 4; j++)
            acc[i][j] = (f32x4){0.f, 0.f, 0.f, 0.f};

    STAGE8(0, 0)
    int buf = 0;
    const int NT = K >> 5;
    for (int t = 0; t < NT; t++) {
        __syncthreads();                 // buf staged (vmcnt drain) + prev reads done
        if (t + 1 < NT) STAGE8(buf ^ 1, (t + 1) << 5)

        const u16* Lb = (const u16*)smem + buf * (2048 * 8);
        bf16x8 ah[2], al[2], bh[4], bl[4];
#pragma unroll
        for (int i = 0; i < 2; i++) {
            const int off = (wy * 32 + i * 16 + l15) * 32 + cA;
            ah[i] = *(const bf16x8*)(Lb + off);
            al[i] = *(const bf16x8*)(Lb + 512 * 8 + off);
        }
#pragma unroll
        for (int j = 0; j < 4; j++) {
            const int off = (wx * 64 + j * 16 + l15) * 32 + cA;
            bh[j] = *(const bf16x8*)(Lb + 1024 * 8 + off);
            bl[j] = *(const bf16x8*)(Lb + 1536 * 8 + off);
        }

#pragma unroll
        for (int i = 0; i < 2; i++)
#pragma unroll
            for (int j = 0; j < 4; j++) {
                acc[i][j] = __builtin_amdgcn_mfma_f32_16x16x32_bf16(
                    ah[i], bh[j], acc[i][j], 0, 0, 0);
                acc[i][j] = __builtin_amdgcn_mfma_f32_16x16x32_bf16(
                    ah[i], bl[j], acc[i][j], 0, 0, 0);
                acc[i][j] = __builtin_amdgcn_mfma_f32_16x16x32_bf16(
                    al[i], bh[j], acc[i][j], 0, 0, 0);
            }
        buf ^= 1;
    }
#undef STAGE8

    const int mBase = (int)mTile + wy * 32;
    const int nBase = (int)nTile + wx * 64;
#pragma unroll
    for (int i = 0; i < 2; i++) {
#pragma unroll
        for (int j = 0; j < 4; j++) {
            const int n = nBase + j * 16 + l15;
            const float bv = BIAS ? bias[n] : 0.0f;
#pragma unroll
            for (int r = 0; r < 4; r++) {
                const int m = mBase + i * 16 + quad * 4 + r;
                float v = acc[i][j][r] + bv;
                if (RELU) v = fmaxf(v, 0.0f);
                const long o = cOff + (long)m * ldc + n;
                if (WF32) C[o] = v;
                if (WSPLIT) {
                    u16 h, l;
                    splitf(v, h, l);
                    Chi[o] = h;
                    Clo[o] = l;
                }
            }
        }
    }
}

// ---------------------------------------------------------------------------
// 4-wave split-bf16 GEMM (kept for KXT, MI=1: tile 32x128). LDS structure +
// XCD swizzle as in round 1/2.
// ---------------------------------------------------------------------------
template <int MI, int BIAS, int RELU, int WF32, int WSPLIT>
__global__ __launch_bounds__(256, 2) void mgemm_k(
    const u16* __restrict__ Ahi, const u16* __restrict__ Alo,
    const u16* __restrict__ Bhi, const u16* __restrict__ Blo,
    float* __restrict__ C, u16* __restrict__ Chi, u16* __restrict__ Clo,
    const float* __restrict__ bias,
    int M, int N, int K, int lda, int ldb, int ldc,
    long sAoff, long sBoff, long sCoff)
{
    constexpr int ACH = MI * 128;        // 16B chunks per A stream per BK-tile
    constexpr int TOT = 2 * ACH + 1024;  // chunks per buffer (Ahi|Alo|Bhi|Blo)
    __shared__ __align__(16) u16 smem[2 * TOT * 8];

    const int bz = blockIdx.z;
    Ahi += bz * sAoff;  Alo += bz * sAoff;
    Bhi += bz * sBoff;  Blo += bz * sBoff;
    const long cOff = (long)bz * sCoff;

    const int gx = gridDim.x, nwg = gx * gridDim.y;
    int lin = blockIdx.y * gx + blockIdx.x;
    lin = (lin & 7) * (nwg >> 3) + (lin >> 3);
    const int bxs = lin % gx, bys = lin / gx;

    const int tid  = threadIdx.x;
    const int wave = tid >> 6, lane = tid & 63;
    const int quad = lane >> 4, l15 = lane & 15;
    const int wy = wave >> 1, wx = wave & 1;
    const long mTile = (long)bys * (MI * 32);
    const long nTile = (long)bxs * 128;
    const int mBase = (int)mTile + wy * (MI * 16);
    const int nBase = (int)nTile + wx * 64;

    const int fsw = (l15 & 3) ^ ((l15 >> 2) & 3);
    const int cA  = (quad ^ fsw) * 8;

#define STAGE(bufi, koff)                                                     \
    {                                                                         \
        _Pragma("unroll")                                                     \
        for (int s = 0; s < TOT / 256; s++) {                                 \
            const int idx = s * 256 + tid;                                    \
            const u16* sp;  long rowb;  int ldx;  int rel;                    \
            if (idx < ACH)                { sp = Ahi; rel = idx;               rowb = 0; ldx = lda; } \
            else if (idx < 2 * ACH)       { sp = Alo; rel = idx - ACH;         rowb = 0; ldx = lda; } \
            else if (idx < 2 * ACH + 512) { sp = Bhi; rel = idx - 2 * ACH;     rowb = 1; ldx = ldb; } \
            else                          { sp = Blo; rel = idx - 2*ACH - 512; rowb = 1; ldx = ldb; } \
            const long rb = rowb ? nTile : mTile;                             \
            const int r = rel >> 2;                                           \
            const int c = (rel & 3) ^ ((r & 3) ^ ((r >> 2) & 3));             \
            const u16* g = sp + (rb + r) * (long)ldx + (koff) + c * 8;        \
            u16* lp = (u16*)smem + (bufi) * (TOT * 8) + idx * 8;              \
            __builtin_amdgcn_global_load_lds(                                 \
                (const __attribute__((address_space(1))) void*)g,             \
                (__attribute__((address_space(3))) void*)lp, 16, 0, 0);       \
        }                                                                     \
    }

    f32x4 acc[MI][4];
#pragma unroll
    for (int i = 0; i < MI; i++)
#pragma unroll
        for (int j = 0; j < 4; j++)
            acc[i][j] = (f32x4){0.f, 0.f, 0.f, 0.f};

    STAGE(0, 0)
    int buf = 0;
    const int NT = K >> 5;
    for (int t = 0; t < NT; t++) {
        __syncthreads();
        if (t + 1 < NT) STAGE(buf ^ 1, (t + 1) << 5)

        const u16* Lb = (const u16*)smem + buf * (TOT * 8);
        bf16x8 ah[MI], al[MI], bh[4], bl[4];
#pragma unroll
        for (int i = 0; i < MI; i++) {
            const int off = (wy * (MI * 16) + i * 16 + l15) * 32 + cA;
            ah[i] = *(const bf16x8*)(Lb + off);
            al[i] = *(const bf16x8*)(Lb + ACH * 8 + off);
        }
#pragma unroll
        for (int j = 0; j < 4; j++) {
            const int off = (wx * 64 + j * 16 + l15) * 32 + cA;
            bh[j] = *(const bf16x8*)(Lb + 2 * ACH * 8 + off);
            bl[j] = *(const bf16x8*)(Lb + 2 * ACH * 8 + 512 * 8 + off);
        }

#pragma unroll
        for (int i = 0; i < MI; i++)
#pragma unroll
            for (int j = 0; j < 4; j++) {
                acc[i][j] = __builtin_amdgcn_mfma_f32_16x16x32_bf16(
                    ah[i], bh[j], acc[i][j], 0, 0, 0);
                acc[i][j] = __builtin_amdgcn_mfma_f32_16x16x32_bf16(
                    ah[i], bl[j], acc[i][j], 0, 0, 0);
                acc[i][j] = __builtin_amdgcn_mfma_f32_16x16x32_bf16(
                    al[i], bh[j], acc[i][j], 0, 0, 0);
            }
        buf ^= 1;
    }
#undef STAGE

#pragma unroll
    for (int i = 0; i < MI; i++) {
#pragma unroll
        for (int j = 0; j < 4; j++) {
            const int n = nBase + j * 16 + l15;
            const float bv = BIAS ? bias[n] : 0.0f;
#pragma unroll
            for (int r = 0; r < 4; r++) {
                const int m = mBase + i * 16 + quad * 4 + r;
                float v = acc[i][j][r] + bv;
                if (RELU) v = fmaxf(v, 0.0f);
                const long o = cOff + (long)m * ldc + n;
                if (WF32) C[o] = v;
                if (WSPLIT) {
                    u16 h, l;
                    splitf(v, h, l);
                    Chi[o] = h;
                    Clo[o] = l;
                }
            }
        }
    }
}

// ---------------------------------------------------------------------------
// Fused mask path, pass A: per-head Gram tile S = G G^T via one-shot LDS
// staging. MFMA order (s{i{j{hh,hl,lh}}}) IDENTICAL to sextract_k -> same
// bits. NEW: publishes per-tile per-row maxima (tmaxU) so pass B can skip
// tiles that provably contain no entries (exact test: tmax is the max of
// the exact bits pass B would recompute; mapf roundtrip is bijective).
// ---------------------------------------------------------------------------
__global__ __launch_bounds__(256, 2) void smax_k(
    const u16* __restrict__ Ghi, const u16* __restrict__ Glo,
    unsigned* __restrict__ rowmaxU, unsigned* __restrict__ tmaxU)
{
    __shared__ __align__(16) u16 gs[4096 * 8];   // 64 KB: Ahi|Alo|Bhi|Blo
    const int h = blockIdx.z;
    const int lda = HH * QQ;
    const u16* Gh = Ghi + h * QQ;
    const u16* Gl = Glo + h * QQ;

    const int gx = gridDim.x, nwg = gx * gridDim.y;   // 16, 256
    int lin = blockIdx.y * gx + blockIdx.x;
    lin = (lin & 7) * (nwg >> 3) + (lin >> 3);
    const int bxs = lin % gx, bys = lin / gx;

    const int tid  = threadIdx.x;
    const int wave = tid >> 6, lane = tid & 63;
    const int quad = lane >> 4, l15 = lane & 15;
    const int wy = wave >> 1, wx = wave & 1;
    const int rT = bys * 128, cT = bxs * 128;
    const int rB = rT + wy * 64;

    // stage: 4 streams x 1024 chunks (128 rows x 8), 16 loads/thread.
#define SSTG(src, rowbase, dstbase)                                           \
    _Pragma("unroll")                                                         \
    for (int it = 0; it < 4; it++) {                                          \
        const int idx = it * 256 + tid;                                       \
        const int r = idx >> 3;                                               \
        const int c = (idx & 7) ^ (r & 7);                                    \
        __builtin_amdgcn_global_load_lds(                                     \
            (const __attribute__((address_space(1))) void*)(src + (long)((rowbase) + r) * lda + c * 8), \
            (__attribute__((address_space(3))) void*)((u16*)gs + (dstbase) + idx * 8), 16, 0, 0); \
    }
    SSTG(Gh, rT, 0)
    SSTG(Gl, rT, 8192)
    SSTG(Gh, cT, 16384)
    SSTG(Gl, cT, 24576)
#undef SSTG
    __syncthreads();

    bf16x8 ah[2][4], al[2][4], bh[2][4], bl[2][4];
#pragma unroll
    for (int s = 0; s < 2; s++) {
#pragma unroll
        for (int i = 0; i < 4; i++) {
            const int ra = wy * 64 + i * 16 + l15;
            const int ca = ((s * 4 + quad) ^ (ra & 7)) * 8;
            ah[s][i] = *(const bf16x8*)(gs + ra * 64 + ca);
            al[s][i] = *(const bf16x8*)(gs + 8192 + ra * 64 + ca);
            const int rb = wx * 64 + i * 16 + l15;
            const int cb = ((s * 4 + quad) ^ (rb & 7)) * 8;
            bh[s][i] = *(const bf16x8*)(gs + 16384 + rb * 64 + cb);
            bl[s][i] = *(const bf16x8*)(gs + 24576 + rb * 64 + cb);
        }
    }

    f32x4 acc[4][4];
#pragma unroll
    for (int i = 0; i < 4; i++)
#pragma unroll
        for (int j = 0; j < 4; j++)
            acc[i][j] = (f32x4){0.f, 0.f, 0.f, 0.f};

#pragma unroll
    for (int s = 0; s < 2; s++)
#pragma unroll
        for (int i = 0; i < 4; i++)
#pragma unroll
            for (int j = 0; j < 4; j++) {
                acc[i][j] = __builtin_amdgcn_mfma_f32_16x16x32_bf16(ah[s][i], bh[s][j], acc[i][j], 0, 0, 0);
                acc[i][j] = __builtin_amdgcn_mfma_f32_16x16x32_bf16(ah[s][i], bl[s][j], acc[i][j], 0, 0, 0);
                acc[i][j] = __builtin_amdgcn_mfma_f32_16x16x32_bf16(al[s][i], bh[s][j], acc[i][j], 0, 0, 0);
            }

    const unsigned tBase = (unsigned)((((h << 4) + bys) << 4) + bxs) * 128u;
#pragma unroll
    for (int i = 0; i < 4; i++)
#pragma unroll
        for (int r = 0; r < 4; r++) {
            float mx = acc[i][0][r];
#pragma unroll
            for (int j = 1; j < 4; j++) mx = fmaxf(mx, acc[i][j][r]);
#pragma unroll
            for (int off = 1; off < 16; off <<= 1)
                mx = fmaxf(mx, __shfl_xor(mx, off, 64));
            if (l15 == 0) {
                const int lr = wy * 64 + i * 16 + quad * 4 + r;
                const unsigned mv = mapf(mx);
                atomicMax(&rowmaxU[h * NN + rT + lr], mv);
                atomicMax(&tmaxU[tBase + lr], mv);
            }
        }
}

// ---------------------------------------------------------------------------
// Fused mask path, pass B: EARLY-EXIT via tmaxU (exact: same bits as the
// recompute below), else recompute IDENTICAL S tile (same per-(s,i,j) MFMA
// order and fragment values as smax -> same bits), threshold, count, emit.
// ---------------------------------------------------------------------------
__global__ __launch_bounds__(256) void sextract_k(
    const u16* __restrict__ Ghi, const u16* __restrict__ Glo,
    const unsigned* __restrict__ rowmaxU, const unsigned* __restrict__ tmaxU,
    int* __restrict__ rowcnt,
    unsigned int* __restrict__ entries, int* __restrict__ counter)
{
    const int h = blockIdx.z;
    const u16* Ah = Ghi + h * QQ;
    const u16* Al = Glo + h * QQ;
    const int lda = HH * QQ;

    const int gx = gridDim.x, nwg = gx * gridDim.y;
    int lin = blockIdx.y * gx + blockIdx.x;
    lin = (lin & 7) * (nwg >> 3) + (lin >> 3);
    const int bxs = lin % gx, bys = lin / gx;

    const int tid  = threadIdx.x;
    const int wave = tid >> 6, lane = tid & 63;
    const int quad = lane >> 4, l15 = lane & 15;
    const int wy = wave >> 1, wx = wave & 1;
    const int rB = bys * 128 + wy * 64;
    const int cB = bxs * 128 + wx * 64;

    __shared__ float thrS[128];
    __shared__ unsigned lbuf[LCAP];
    __shared__ int lcnt, gbase, anyf;
    if (tid == 0) { lcnt = 0; anyf = 0; }
    if (tid < 128) {
        float mx = unmapf(rowmaxU[h * NN + bys * 128 + tid]);
        float thr = (fabsf(mx) > 0.5f) ? mx - 0.5f : 3.402823466e38f;
        thrS[tid] = thr;
        float tm = unmapf(tmaxU[(unsigned)((((h << 4) + bys) << 4) + bxs) * 128u + tid]);
        if (tm >= thr) atomicAdd(&anyf, 1);
    }
    __syncthreads();
    if (anyf == 0) return;   // tile provably empty (exact bit-level test)

    bf16x8 ah[2][4], al[2][4], bh[2][4], bl[2][4];
#pragma unroll
    for (int s = 0; s < 2; s++) {
        const int kk = s * 32 + quad * 8;
#pragma unroll
        for (int i = 0; i < 4; i++) {
            long ar = (long)(rB + i * 16 + l15) * lda + kk;
            ah[s][i] = *(const bf16x8*)(Ah + ar);
            al[s][i] = *(const bf16x8*)(Al + ar);
            long br = (long)(cB + i * 16 + l15) * lda + kk;
            bh[s][i] = *(const bf16x8*)(Ah + br);
            bl[s][i] = *(const bf16x8*)(Al + br);
        }
    }

    f32x4 acc[4][4];
#pragma unroll
    for (int i = 0; i < 4; i++)
#pragma unroll
        for (int j = 0; j < 4; j++)
            acc[i][j] = (f32x4){0.f, 0.f, 0.f, 0.f};

#pragma unroll
    for (int s = 0; s < 2; s++)
#pragma unroll
        for (int i = 0; i < 4; i++)
#pragma unroll
            for (int j = 0; j < 4; j++) {
                acc[i][j] = __builtin_amdgcn_mfma_f32_16x16x32_bf16(ah[s][i], bh[s][j], acc[i][j], 0, 0, 0);
                acc[i][j] = __builtin_amdgcn_mfma_f32_16x16x32_bf16(ah[s][i], bl[s][j], acc[i][j], 0, 0, 0);
                acc[i][j] = __builtin_amdgcn_mfma_f32_16x16x32_bf16(al[s][i], bh[s][j], acc[i][j], 0, 0, 0);
            }

#pragma unroll
    for (int i = 0; i < 4; i++) {
#pragma unroll
        for (int r = 0; r < 4; r++) {
            const int lr  = wy * 64 + i * 16 + quad * 4 + r;
            const int row = h * NN + rB + i * 16 + quad * 4 + r;
            const float thr = thrS[lr];

            int c = 0;
#pragma unroll
            for (int j = 0; j < 4; j++) c += (acc[i][j][r] >= thr) ? 1 : 0;
            int cs = c;
#pragma unroll
            for (int off = 1; off < 16; off <<= 1) cs += __shfl_xor(cs, off, 64);
            if (l15 == 0 && cs > 0) atomicAdd(&rowcnt[row], cs);

#pragma unroll
            for (int j = 0; j < 4; j++) {
                if (acc[i][j][r] >= thr) {
                    unsigned ent = ((unsigned)row << 11) |
                                   (unsigned)(cB + j * 16 + l15);
                    int s2 = atomicAdd(&lcnt, 1);
                    if (s2 < LCAP) {
                        lbuf[s2] = ent;
                    } else {
                        unsigned p = (unsigned)atomicAdd(counter, 1);
                        if (p < ENTRY_CAP) entries[p] = ent;
                    }
                }
            }
        }
    }

    __syncthreads();
    int n = lcnt;
    if (n > LCAP) n = LCAP;
    if (n > 0) {
        if (tid == 0) gbase = atomicAdd(counter, n);
        __syncthreads();
        for (int i2 = tid; i2 < n; i2 += 256) {
            unsigned p = (unsigned)(gbase + i2);
            if (p < ENTRY_CAP) entries[p] = lbuf[i2];
        }
    }
}

// ---------------------------------------------------------------------------
// split / splitw(+rowmax/tmax zero) / splitc(+attnT copy) / zero / buildcsr /
// apply(inline wrecip) / ff2red(+attnT writeback) / transpose
// ---------------------------------------------------------------------------
__global__ __launch_bounds__(256) void split_k(
    const float* __restrict__ src, u16* __restrict__ hi, u16* __restrict__ lo)
{
    int i = blockIdx.x * 256 + threadIdx.x;
    float4 v = ((const float4*)src)[i];
    ushort4 hv, lv;
    splitf(v.x, hv.x, lv.x);
    splitf(v.y, hv.y, lv.y);
    splitf(v.z, hv.z, lv.z);
    splitf(v.w, hv.w, lv.w);
    ((ushort4*)hi)[i] = hv;
    ((ushort4*)lo)[i] = lv;
}

// initial split that also seeds attnT = X^T (replaces initattn for layer 0)
__global__ __launch_bounds__(256) void splitc_k(
    const float* __restrict__ src, u16* __restrict__ hi, u16* __restrict__ lo,
    float* __restrict__ cpy)
{
    int i = blockIdx.x * 256 + threadIdx.x;
    float4 v = ((const float4*)src)[i];
    ((float4*)cpy)[i] = v;
    ushort4 hv, lv;
    splitf(v.x, hv.x, lv.x);
    splitf(v.y, hv.y, lv.y);
    splitf(v.z, hv.z, lv.z);
    splitf(v.w, hv.w, lv.w);
    ((ushort4*)hi)[i] = hv;
    ((ushort4*)lo)[i] = lv;
}

__global__ __launch_bounds__(256) void splitw_k(
    const float* __restrict__ K_, const float* __restrict__ V_,
    const float* __restrict__ W1_, const float* __restrict__ W2_,
    u16* __restrict__ Khi, u16* __restrict__ Klo,
    u16* __restrict__ Vhi, u16* __restrict__ Vlo,
    u16* __restrict__ W1hi, u16* __restrict__ W1lo,
    u16* __restrict__ W2hi, u16* __restrict__ W2lo,
    unsigned* __restrict__ zrow, unsigned* __restrict__ ztmax)
{
    int i = blockIdx.x * 256 + threadIdx.x;
    if (i < 16384) zrow[i] = 0u;      // zero rowmaxU + rowcnt (contiguous)
    if (i < 131072) ztmax[i] = 0u;    // zero per-tile row maxima
    const float* s;
    u16 *h, *l;
    int off;
    if (i < 32768)       { s = K_;  h = Khi;  l = Klo;  off = i; }
    else if (i < 294912) { s = V_;  h = Vhi;  l = Vlo;  off = i - 32768; }
    else if (i < 557056) { s = W1_; h = W1hi; l = W1lo; off = i - 294912; }
    else                 { s = W2_; h = W2hi; l = W2lo; off = i - 557056; }
    float4 v = ((const float4*)s)[off];
    ushort4 hv, lv;
    splitf(v.x, hv.x, lv.x);
    splitf(v.y, hv.y, lv.y);
    splitf(v.z, hv.z, lv.z);
    splitf(v.w, hv.w, lv.w);
    ((ushort4*)h)[off] = hv;
    ((ushort4*)l)[off] = lv;
}

__global__ void zero_k(int* __restrict__ counters)
{
    if (threadIdx.x < LL) counters[threadIdx.x] = 0;
}

__global__ __launch_bounds__(256) void buildcsr_k(
    const unsigned int* __restrict__ entries, const int* __restrict__ counter,
    unsigned int* __restrict__ csr, int* __restrict__ colOff)
{
    __shared__ int hist[NN];
    __shared__ int part[256];
    const int t = threadIdx.x;
    int cnt = *counter;
    if (cnt > ENTRY_CAP) cnt = ENTRY_CAP;

    for (int i = t; i < NN; i += 256) hist[i] = 0;
    __syncthreads();
    for (int i = t; i < cnt; i += 256)
        atomicAdd(&hist[entries[i] & 2047], 1);
    __syncthreads();

    int e[8];
    int s = 0;
#pragma unroll
    for (int i = 0; i < 8; i++) { e[i] = s; s += hist[t * 8 + i]; }
    part[t] = s;
    __syncthreads();
    for (int off = 1; off < 256; off <<= 1) {
        int x = (t >= off) ? part[t - off] : 0;
        __syncthreads();
        part[t] += x;
        __syncthreads();
    }
    int base = (t > 0) ? part[t - 1] : 0;
    int my[8];
#pragma unroll
    for (int i = 0; i < 8; i++) my[i] = base + e[i];
#pragma unroll
    for (int i = 0; i < 8; i++) colOff[t * 8 + i] = my[i];
    if (t == 255) colOff[NN] = part[255];
    __syncthreads();
#pragma unroll
    for (int i = 0; i < 8; i++) hist[t * 8 + i] = my[i];
    __syncthreads();

    for (int i = t; i < cnt; i += 256) {
        unsigned v = entries[i];
        int slot = atomicAdd(&hist[v & 2047], 1);
        csr[slot] = v;
    }
}

__global__ __launch_bounds__(256) void apply_k(
    const unsigned int* __restrict__ csr, const int* __restrict__ colOff,
    const unsigned* __restrict__ rowmaxU, const int* __restrict__ rowcnt,
    const float* __restrict__ Yt, float* __restrict__ attnT)
{
    const int total = colOff[NN];
    const int tid = threadIdx.x;

    for (int base = blockIdx.x * CHUNK; base < total;
         base += gridDim.x * CHUNK) {
        int end = base + CHUNK;
        if (end > total) end = total;

        float a0 = 0.0f, a1 = 0.0f;
        int curM = -1;
        for (int e = base; e < end; e++) {
            unsigned v = csr[e];
            int m = v & 2047;
            int row = (int)(v >> 11);
            if (m != curM) {
                if (curM >= 0) {
                    atomicAdd(&attnT[(long)curM * DD + tid], a0);
                    atomicAdd(&attnT[(long)curM * DD + tid + 256], a1);
                }
                curM = m;
                a0 = a1 = 0.0f;
            }
            float mx = unmapf(rowmaxU[row]);
            float w = (fabsf(mx) > 0.5f)
                          ? 1.0f / fmaxf((float)rowcnt[row], 1.0f) : 0.0f;
            const float* y = Yt + (long)row * DD;
            a0 += w * y[tid];
            a1 += w * y[tid + 256];
        }
        if (curM >= 0) {
            atomicAdd(&attnT[(long)curM * DD + tid], a0);
            atomicAdd(&attnT[(long)curM * DD + tid + 256], a1);
        }
    }
}

__global__ __launch_bounds__(256) void ff2red_k(
    const float* __restrict__ Cpart, const float* __restrict__ b2,
    float* __restrict__ attnT, float* __restrict__ Xn,
    u16* __restrict__ Xhi, u16* __restrict__ Xlo)
{
    int i = blockIdx.x * 256 + threadIdx.x;
    float4 v0 = ((const float4*)(Cpart))[i];
    float4 v1 = ((const float4*)(Cpart + 1048576))[i];
    float4 v2 = ((const float4*)(Cpart + 2097152))[i];
    float4 v3 = ((const float4*)(Cpart + 3145728))[i];
    float4 bv = ((const float4*)b2)[i & 127];
    float4 rv = ((const float4*)attnT)[i];
    float4 o;
    o.x = v0.x + v1.x + v2.x + v3.x + bv.x + rv.x;
    o.y = v0.y + v1.y + v2.y + v3.y + bv.y + rv.y;
    o.z = v0.z + v1.z + v2.z + v3.z + bv.z + rv.z;
    o.w = v0.w + v1.w + v2.w + v3.w + bv.w + rv.w;
    ((float4*)Xn)[i] = o;
    ((float4*)attnT)[i] = o;           // seed next layer's residual base
    ushort4 hv, lv;
    splitf(o.x, hv.x, lv.x);
    splitf(o.y, hv.y, lv.y);
    splitf(o.z, hv.z, lv.z);
    splitf(o.w, hv.w, lv.w);
    ((ushort4*)Xhi)[i] = hv;
    ((ushort4*)Xlo)[i] = lv;
}

__global__ __launch_bounds__(256) void transpose_k(
    const float* __restrict__ src, float* __restrict__ dst, int R, int C)
{
    __shared__ float t[32][33];
    int tx = threadIdx.x & 31, ty = threadIdx.x >> 5;
    int c0 = blockIdx.x * 32, r0 = blockIdx.y * 32;
#pragma unroll
    for (int k = 0; k < 4; k++)
        t[ty + 8 * k][tx] = src[(long)(r0 + ty + 8 * k) * C + c0 + tx];
    __syncthreads();
#pragma unroll
    for (int k = 0; k < 4; k++)
        dst[(long)(c0 + ty + 8 * k) * R + r0 + tx] = t[tx][ty + 8 * k];
}

// ---------------------------------------------------------------------------
// Workspace layout (~88.2 MB < proven 94.4 MB).
// ---------------------------------------------------------------------------
extern "C" void kernel_launch(void* const* d_in, const int* in_sizes, int n_in,
                              void* d_out, int out_size, void* d_ws, size_t ws_size,
                              hipStream_t stream)
{
    const float* X0 = (const float*)d_in[0];
    const float* Kw = (const float*)d_in[1];
    const float* Vw = (const float*)d_in[2];
    const float* W1 = (const float*)d_in[3];
    const float* b1 = (const float*)d_in[4];
    const float* W2 = (const float*)d_in[5];
    const float* b2 = (const float*)d_in[6];
    float* out = (float*)d_out;

    float* R0    = (float*)d_ws;
    float* Yt    = R0;                       // 4,194,304  [H,NN,DD] fp32
    u16*   ff1hi = (u16*)(R0 + 4194304);
    u16*   ff1lo = (u16*)(R0 + 6291456);
    float* Cpart = R0 + 8388608;             // 4,194,304
    float* attnT = R0 + 12582912;            // 1,048,576

    float* ext = R0 + 13631488;
    u16* KXThi = (u16*)ext;                  // 262,144 words
    u16* KXTlo = (u16*)(ext + 262144);
    float* XbufA = ext + 524288;             // 1,048,576
    float* XbufB = ext + 1572864;            // 1,048,576
    u16* Xhi  = (u16*)(ext + 2621440);       // 524,288 words
    u16* Xlo  = (u16*)(ext + 3145728);
    u16* athi = (u16*)(ext + 3670016);
    u16* atlo = (u16*)(ext + 4194304);
    u16* Khi  = (u16*)(ext + 4718592);       // 65,536 words
    u16* Klo  = (u16*)(ext + 4784128);
    u16* Vhi  = (u16*)(ext + 4849664);       // 524,288 words
    u16* Vlo  = (u16*)(ext + 5373952);
    u16* W1hi = (u16*)(ext + 5898240);
    u16* W1lo = (u16*)(ext + 6422528);
    u16* W2hi = (u16*)(ext + 6946816);
    u16* W2lo = (u16*)(ext + 7471104);
    unsigned int* entries = (unsigned int*)(ext + 8003584);  // 131,072
    unsigned int* csr     = (unsigned int*)(ext + 8134656);  // 131,072
    int* colOff   = (int*)(ext + 8265728);   // 2,112
    int* counters = (int*)(ext + 8267840);   // 64
    unsigned* rowmaxU = (unsigned*)(ext + 8267904);  // 8,192
    int* rowcnt   = (int*)(ext + 8276096);   // 8,192 (contiguous after rowmaxU)
    unsigned* tmaxU = (unsigned*)(ext + 8284288);    // 131,072 (per-tile row maxima)

    zero_k<<<1, 64, 0, stream>>>(counters);

    // XT0 = X0^T [N, D]; split to bf16 hi/lo and seed attnT = XT0
    transpose_k<<<dim3(NN / 32, DD / 32), 256, 0, stream>>>(X0, XbufA, DD, NN);
    splitc_k<<<dim3(1024), 256, 0, stream>>>(XbufA, Xhi, Xlo, attnT);

    float* Xc = XbufA;
    for (int li = 0; li < LL; li++) {
        float* Xn = (li & 1) ? XbufA : XbufB;

        // 0) split this layer's weights to bf16 hi/lo (+ zero rowmax/rowcnt/tmax)
        splitw_k<<<dim3(3200), 256, 0, stream>>>(
            Kw + (long)li * 131072, Vw + (long)li * 1048576,
            W1 + (long)li * 1048576, W2 + (long)li * 1048576,
            Khi, Klo, Vhi, Vlo, W1hi, W1lo, W2hi, W2lo, rowmaxU, tmaxU);

        // 1) KXT = XT @ Kw^T  [2048, 256], K=512 -> hi/lo. MI=1: 128 blocks.
        mgemm_k<1, 0, 0, 0, 1><<<dim3(2, 64, 1), 256, 0, stream>>>(
            Xhi, Xlo, Khi, Klo, nullptr, KXThi, KXTlo, nullptr,
            NN, HH * QQ, DD, DD, DD, HH * QQ, 0, 0, 0);

        // 2) fused mask path: no S materialization
        smax_k<<<dim3(16, 16, HH), 256, 0, stream>>>(KXThi, KXTlo, rowmaxU, tmaxU);
        sextract_k<<<dim3(16, 16, HH), 256, 0, stream>>>(
            KXThi, KXTlo, rowmaxU, tmaxU, rowcnt, entries, counters + li);
        buildcsr_k<<<dim3(1), 256, 0, stream>>>(entries, counters + li, csr, colOff);

        // 4) Yt_h = XT @ V_h^T  [NN, DD] fp32, batch H. 8-wave: 64 blk/head.
        mgemm8_k<0, 0, 1, 0><<<dim3(4, 16, HH), 512, 0, stream>>>(
            Xhi, Xlo, Vhi, Vlo, Yt, nullptr, nullptr, nullptr,
            DD, DD, DD, DD, 0, (long)DD * DD, (long)NN * DD);

        // 5) attnT (= XT residual, maintained by ff2red/splitc) += sparse combine
        apply_k<<<dim3(APPLY_BLOCKS), 256, 0, stream>>>(
            csr, colOff, rowmaxU, rowcnt, Yt, attnT);
        split_k<<<dim3(1024), 256, 0, stream>>>(attnT, athi, atlo);

        // 6) ff1 = relu(attnT @ W1^T + b1)  [NN, DFF] -> hi/lo. 256 blocks.
        mgemm8_k<1, 1, 0, 1><<<dim3(16, 16, 1), 512, 0, stream>>>(
            athi, atlo, W1hi, W1lo, nullptr, ff1hi, ff1lo,
            b1 + (long)li * DFFC,
            DD, DD, DD, DFFC, 0, 0, 0);

        // 7) FF2 split-K=4: 64 blocks x 4.
        mgemm8_k<0, 0, 1, 0><<<dim3(4, 16, 4), 512, 0, stream>>>(
            ff1hi, ff1lo, W2hi, W2lo, Cpart, nullptr, nullptr, nullptr,
            512, DFFC, DFFC, DD, 512, 512, (long)NN * DD);
        ff2red_k<<<dim3(1024), 256, 0, stream>>>(
            Cpart, b2 + (long)li * DD, attnT, Xn, Xhi, Xlo);

        Xc = Xn;
    }

    // out = XT_final^T  [D, N]
    transpose_k<<<dim3(DD / 32, NN / 32), 256, 0, stream>>>(Xc, out, NN, DD);
}